// Round 1
// baseline (521.861 us; speedup 1.0000x reference)
//
#include <hip/hip_runtime.h>
#include <hip/hip_fp16.h>
#include <cstdio>
#include <cstdint>

#define HH 512
#define WW 512
#define CC 32
#define BB 2
#define NN 120000
#define HWPIX (HH*WW)
#define NPTS (BB*NN)          // 240000 occupied points
#define NPIX (BB*HWPIX)       // 524288 pixels (pixel-dense storage)
#define NBLK (NPIX/256)       // 2048 pixel windows

__device__ __forceinline__ void h8_to_f8(float4 raw, float* o) {
    const __half2* h = (const __half2*)&raw;
    #pragma unroll
    for (int i = 0; i < 4; ++i) {
        float2 f = __half22float2(h[i]);
        o[2 * i] = f.x; o[2 * i + 1] = f.y;
    }
}

// ---------------- prep: compose weights + vecs + zero flag map (one kernel) ----------------
// M layout (floats): [0:1024) MqT, [1024:2048) MkT, [2048:3072) MvT, [3072:4096) owT
// V layout (floats): [0:32) bq'=W1@bq+in_b[:32], [32:64) bk'=W2@bk, [64:96) bv'=W3@bv,
// [96:128) PWy, [128:160) PWx, [160:192) pb3=W3@pos_b
__global__ __launch_bounds__(256) void prep(const float* __restrict__ wq, const float* __restrict__ wk,
                          const float* __restrict__ wv, const float* __restrict__ in_w,
                          const float* __restrict__ out_w,
                          const float* __restrict__ bq, const float* __restrict__ bk,
                          const float* __restrict__ bv, const float* __restrict__ in_b,
                          const float* __restrict__ pos_w, const float* __restrict__ pos_b,
                          float* __restrict__ M, float* __restrict__ V, int* __restrict__ fmap_i) {
    int blk = blockIdx.x;
    if (blk < 16) {
        int tid = blk * 256 + threadIdx.x;   // 0..4095
        int which = tid >> 10;
        int e = tid & 1023;
        int cp = e & 31;
        int j  = e >> 5;
        if (which < 3) {
            const float* w = (which == 0) ? wq : ((which == 1) ? wk : wv);
            const float* Wrow = in_w + (which * 32 + cp) * 32;
            float acc = 0.f;
            #pragma unroll
            for (int t = 0; t < 32; ++t) acc += Wrow[t] * w[t * 32 + j];
            M[which * 1024 + j * 32 + cp] = acc;
        } else {
            M[3 * 1024 + j * 32 + cp] = out_w[cp * 32 + j];
        }
    } else if (blk == 16) {
        int tid = threadIdx.x;
        if (tid < 32) {
            float a = 0.f, b = 0.f, c = 0.f;
            #pragma unroll
            for (int t = 0; t < 32; ++t) {
                a += in_w[tid * 32 + t] * bq[t];
                b += in_w[(32 + tid) * 32 + t] * bk[t];
                c += in_w[(64 + tid) * 32 + t] * bv[t];
            }
            V[tid]      = a + in_b[tid];
            V[32 + tid] = b;
            V[64 + tid] = c;
        } else if (tid < 128) {
            int grp = (tid - 32) >> 5;   // 0=PWy 1=PWx 2=pb3
            int cp  = tid & 31;
            float acc = 0.f;
            #pragma unroll
            for (int t = 0; t < 32; ++t) {
                float src = (grp == 0) ? pos_w[t * 2 + 0] : ((grp == 1) ? pos_w[t * 2 + 1] : pos_b[t]);
                acc += in_w[(64 + cp) * 32 + t] * src;
            }
            V[96 + grp * 32 + cp] = acc;
        }
    } else {
        // blocks 17..80: zero the 512 KB flag map (131072 ints; 64 blocks x 256 thr x 8 ints)
        int base = (blk - 17) * 2048 + threadIdx.x * 8;
        int4 z = {0, 0, 0, 0};
        *(int4*)(fmap_i + base)     = z;
        *(int4*)(fmap_i + base + 4) = z;
    }
}

// ---------------- stage1: point-parallel LN + fused q/k/v linears (pixel-dense out) ----------------
// Coalesced feats/coors reads; writes q (64 B) + kv (128 B = 1 line) at pixel slots + flag byte.
__global__ __launch_bounds__(256) void stage1(const float* __restrict__ feats,
                                              const int* __restrict__ coors,
                                              const float* __restrict__ ln_w,
                                              const float* __restrict__ ln_b,
                                              const float* __restrict__ M,
                                              const float* __restrict__ V,
                                              __half* __restrict__ qh,
                                              __half* __restrict__ kvh,
                                              unsigned char* __restrict__ fmap) {
    int gp = blockIdx.x * 256 + threadIdx.x;
    if (gp >= NPTS) return;
    int b = (gp >= NN) ? 1 : 0;
    int2 yx = ((const int2*)coors)[gp];
    int pix = (b << 18) + (yx.x << 9) + yx.y;

    const float* fr = feats + ((size_t)gp << 5);
    float x[32];
    #pragma unroll
    for (int k = 0; k < 8; ++k) ((float4*)x)[k] = ((const float4*)fr)[k];

    float s1 = 0.f, s2 = 0.f;
    #pragma unroll
    for (int j = 0; j < 32; ++j) { s1 += x[j]; s2 += x[j] * x[j]; }
    float mu   = s1 * (1.f / 32.f);
    float var  = s2 * (1.f / 32.f) - mu * mu;
    float rstd = rsqrtf(var + 1e-5f);
    #pragma unroll
    for (int j = 0; j < 32; ++j) x[j] = (x[j] - mu) * rstd * ln_w[j] + ln_b[j];

    float acc[32];
    __half2 hbuf[16];

    // q' = x @ Mq + bq'  -> fp16 at pixel slot
    #pragma unroll
    for (int c = 0; c < 32; ++c) acc[c] = V[c];
    #pragma unroll
    for (int j = 0; j < 32; ++j) {
        float xv = x[j];
        #pragma unroll
        for (int c = 0; c < 32; ++c) acc[c] += xv * M[j * 32 + c];
    }
    #pragma unroll
    for (int c = 0; c < 16; ++c) hbuf[c] = __floats2half2_rn(acc[2 * c], acc[2 * c + 1]);
    {
        float4* qd = (float4*)(qh + ((size_t)pix << 5));
        #pragma unroll
        for (int k = 0; k < 4; ++k) qd[k] = ((float4*)hbuf)[k];
    }

    __half2 kvbuf[32];   // 128 B: k halves [0:16), v halves [16:32)

    // k' = x @ Mk + bk'  -> fp16
    #pragma unroll
    for (int c = 0; c < 32; ++c) acc[c] = V[32 + c];
    #pragma unroll
    for (int j = 0; j < 32; ++j) {
        float xv = x[j];
        #pragma unroll
        for (int c = 0; c < 32; ++c) acc[c] += xv * M[1024 + j * 32 + c];
    }
    #pragma unroll
    for (int c = 0; c < 16; ++c) kvbuf[c] = __floats2half2_rn(acc[2 * c], acc[2 * c + 1]);

    // v' = x @ Mv + bv'  -> fp16
    #pragma unroll
    for (int c = 0; c < 32; ++c) acc[c] = V[64 + c];
    #pragma unroll
    for (int j = 0; j < 32; ++j) {
        float xv = x[j];
        #pragma unroll
        for (int c = 0; c < 32; ++c) acc[c] += xv * M[2048 + j * 32 + c];
    }
    #pragma unroll
    for (int c = 0; c < 16; ++c) kvbuf[16 + c] = __floats2half2_rn(acc[2 * c], acc[2 * c + 1]);

    float4* kd = (float4*)(kvh + ((size_t)pix << 6));
    #pragma unroll
    for (int k = 0; k < 8; ++k) kd[k] = ((float4*)kvbuf)[k];

    fmap[pix] = 1;
}

// ---------------- stage23: fused attention + out-proj + canvas write ----------------
// Block = one 256-pixel window. Phase A now runs TWO threads per occupied pixel
// (one per attention head): ~91% lane activity instead of ~46%, and each thread's
// serial load/FMA chain is halved. Heads are fully independent through softmax;
// the 32x32 out-projection is pair-reduced via __shfl_xor(.,1).
__global__ __launch_bounds__(256) void stage23(const unsigned char* __restrict__ fmap,
                                               const __half* __restrict__ qh,
                                               const __half* __restrict__ kvh,
                                               const float* __restrict__ M,
                                               const float* __restrict__ V,
                                               const float* __restrict__ in_b,
                                               const float* __restrict__ out_b,
                                               float* __restrict__ out) {
    __shared__ __half2 lso[256 * 17];   // 17 half2 (68 B) stride per point
    __shared__ int lsp[256];
    __shared__ int woff[4];

    int w = (blockIdx.x & 7) * 256 + (blockIdx.x >> 3);   // XCD-swizzled window index
    int tid = threadIdx.x;
    int pix = w * 256 + tid;

    bool occ = fmap[pix] != 0;
    unsigned long long mask = __ballot(occ);
    int lane = tid & 63, wvi = tid >> 6;
    if (lane == 0) woff[wvi] = __popcll(mask);
    __syncthreads();
    int pre = 0;
    for (int ww = 0; ww < wvi; ++ww) pre += woff[ww];
    int cnt = woff[0] + woff[1] + woff[2] + woff[3];
    int slot = -1;
    if (occ) {
        slot = pre + __popcll(mask & ((1ull << lane) - 1ull));
        lsp[slot] = tid;
    }
    __syncthreads();

    const int DYC[9] = {0,-1,1,0,-1,1,0,-1,1};
    const int DXC[9] = {0,0,0,1,1,1,-1,-1,-1};

    // ---- phase A: attention, thread pair (point, head) ----
    for (int t = tid; t < 2 * cnt; t += 256) {
        int pt = t >> 1;          // point slot
        int h  = t & 1;           // head
        int hb = h << 4;          // channel base of this head
        int pixl = w * 256 + lsp[pt];
        int b = pixl >> 18;
        int p = pixl & (HWPIX - 1);
        int y = p >> 9, x = p & 511;

        // this head's 16 q channels (32 B; pair lanes cover the full 64 B line)
        float qf[16];
        {
            const float4* q4 = (const float4*)(qh + ((size_t)pixl << 5)) + (h << 1);
            h8_to_f8(q4[0], qf); h8_to_f8(q4[1], qf + 8);
        }

        // 9 taps: validity is arithmetic + one independent flag byte each
        int np[9];
        bool nv[9];
        #pragma unroll
        for (int s = 0; s < 9; ++s) {
            int sy = y + DYC[s], sx = x + DXC[s];
            bool inb = (sy >= 0) & (sy < HH) & (sx >= 0) & (sx < WW);
            int npx = (b << 18) + (sy << 9) + sx;
            np[s] = npx;
            nv[s] = inb ? (fmap[npx] != 0) : false;
        }

        float eb = 0.f;
        #pragma unroll
        for (int c = 0; c < 16; ++c) eb += qf[c] * in_b[32 + hb + c];

        float lg[9];
        #pragma unroll
        for (int s = 0; s < 9; ++s) {
            float d = eb;
            if (nv[s]) {
                const float4* kp = (const float4*)(kvh + ((size_t)np[s] << 6)) + (h << 1);
                float kf[16];
                h8_to_f8(kp[0], kf); h8_to_f8(kp[1], kf + 8);
                #pragma unroll
                for (int c = 0; c < 16; ++c) d += qf[c] * kf[c];
            }
            lg[s] = d * 0.25f;   // 1/sqrt(HD=16)
        }
        float mx = lg[0];
        #pragma unroll
        for (int s = 1; s < 9; ++s) mx = fmaxf(mx, lg[s]);
        float lsum = 0.f;
        #pragma unroll
        for (int s = 0; s < 9; ++s) { lg[s] = __expf(lg[s] - mx); lsum += lg[s]; }

        float o[16];
        #pragma unroll
        for (int c = 0; c < 16; ++c) o[c] = 0.f;
        float wdy = 0.f, wdx = 0.f, woc = 0.f;
        #pragma unroll
        for (int s = 0; s < 9; ++s) {
            if (nv[s]) {
                float ws = lg[s];
                const float4* vp = (const float4*)(kvh + ((size_t)np[s] << 6)) + 4 + (h << 1);
                float vf[16];
                h8_to_f8(vp[0], vf); h8_to_f8(vp[1], vf + 8);
                #pragma unroll
                for (int c = 0; c < 16; ++c) o[c] += ws * vf[c];
                wdy += ws * (float)DYC[s]; wdx += ws * (float)DXC[s]; woc += ws;
            }
        }
        float rl = 1.f / lsum;
        #pragma unroll
        for (int c = 0; c < 16; ++c) {
            o[c] = (o[c] + wdy * V[96 + hb + c] + wdx * V[128 + hb + c] + woc * V[160 + hb + c]) * rl
                 + in_b[64 + hb + c];
        }

        // out projection partial: this head's 16 rows of the 32x32 matrix
        float acc[32];
        #pragma unroll
        for (int c = 0; c < 32; ++c) acc[c] = 0.f;
        #pragma unroll
        for (int j = 0; j < 16; ++j) {
            float vj = o[j];
            #pragma unroll
            for (int c = 0; c < 32; ++c) acc[c] += vj * M[3072 + (hb + j) * 32 + c];
        }

        // pair-reduce with partner lane (t^1 is always in-wave and active: 2*cnt is even);
        // each thread keeps its own head's 16 output channels and writes 8 half2 to LDS.
        __half2* lrow = lso + pt * 17 + (h << 3);
        #pragma unroll
        for (int i = 0; i < 8; ++i) {
            int c0 = hb + 2 * i, c1 = hb + 2 * i + 1;
            int s0 = ((h ^ 1) << 4) + 2 * i, s1 = s0 + 1;
            float a0 = acc[c0] + __shfl_xor(acc[s0], 1) + out_b[c0];
            float a1 = acc[c1] + __shfl_xor(acc[s1], 1) + out_b[c1];
            lrow[i] = __floats2half2_rn(a0, a1);
        }
    }
    __syncthreads();

    // ---- phase B: canvas write (all 256 threads; 256 B contiguous per wave-instr) ----
    int b = pix >> 18;
    int p = pix & (HWPIX - 1);
    float* outb = out + (size_t)b * CC * HWPIX + p;
    if (occ) {
        const __half2* lrow = lso + slot * 17;
        #pragma unroll
        for (int c2 = 0; c2 < 16; ++c2) {
            float2 f = __half22float2(lrow[c2]);
            outb[(2 * c2) * HWPIX]     = f.x;
            outb[(2 * c2 + 1) * HWPIX] = f.y;
        }
    } else {
        #pragma unroll
        for (int cc = 0; cc < 32; ++cc) outb[cc * HWPIX] = 0.f;
    }
}

extern "C" void kernel_launch(void* const* d_in, const int* in_sizes, int n_in,
                              void* d_out, int out_size, void* d_ws, size_t ws_size,
                              hipStream_t stream) {
    const float* feats = (const float*)d_in[0];
    const int*   coors = (const int*)d_in[1];
    const float* ln_w  = (const float*)d_in[2];
    const float* ln_b  = (const float*)d_in[3];
    const float* wq    = (const float*)d_in[4];
    const float* bq    = (const float*)d_in[5];
    const float* wk    = (const float*)d_in[6];
    const float* bk    = (const float*)d_in[7];
    const float* wv    = (const float*)d_in[8];
    const float* bv    = (const float*)d_in[9];
    const float* pos_w = (const float*)d_in[10];
    const float* pos_b = (const float*)d_in[11];
    const float* in_w  = (const float*)d_in[12];
    const float* in_b  = (const float*)d_in[13];
    const float* out_w = (const float*)d_in[14];
    const float* out_b = (const float*)d_in[15];

    // workspace layout (pixel-dense)
    float*  M    = (float*)d_ws;                                        // 4096
    float*  V    = M + 4096;                                            // 192
    __half* qh   = (__half*)(V + 192);                                  // NPIX*32 halves (33.5 MB)
    __half* kvh  = qh + (size_t)NPIX * 32;                              // NPIX*64 halves (67.1 MB)
    unsigned char* fmap = (unsigned char*)(kvh + (size_t)NPIX * 64);    // NPIX bytes (0.5 MB)
    size_t need = (4096 + 192) * 4 + (size_t)NPIX * 96 * 2 + (size_t)NPIX;
    if (ws_size < need) {
        fprintf(stderr, "kernel_launch: ws too small: %zu < %zu\n", ws_size, need);
        return;
    }

    prep<<<81, 256, 0, stream>>>(wq, wk, wv, in_w, out_w, bq, bk, bv, in_b, pos_w, pos_b,
                                 M, V, (int*)fmap);
    stage1<<<(NPTS + 255) / 256, 256, 0, stream>>>(feats, coors, ln_w, ln_b, M, V, qh, kvh, fmap);
    stage23<<<NBLK, 256, 0, stream>>>(fmap, qh, kvh, M, V, in_b, out_b, (float*)d_out);
}

// Round 2
// 447.726 us; speedup vs baseline: 1.1656x; 1.1656x over previous
//
#include <hip/hip_runtime.h>
#include <hip/hip_fp16.h>
#include <cstdio>
#include <cstdint>

#define HH 512
#define WW 512
#define CC 32
#define BB 2
#define NN 120000
#define HWPIX (HH*WW)
#define NPTS (BB*NN)          // 240000 occupied points
#define NPIX (BB*HWPIX)       // 524288 pixels (pixel-dense storage)
#define NBLK (NPIX/256)       // 2048 pixel windows

__device__ __forceinline__ void h8_to_f8(float4 raw, float* o) {
    const __half2* h = (const __half2*)&raw;
    #pragma unroll
    for (int i = 0; i < 4; ++i) {
        float2 f = __half22float2(h[i]);
        o[2 * i] = f.x; o[2 * i + 1] = f.y;
    }
}

// ---------------- prep: compose weights + vecs + zero flag map (one kernel) ----------------
// M layout (floats): [0:1024) MqT, [1024:2048) MkT, [2048:3072) MvT, [3072:4096) owT
// V layout (floats): [0:32) bq'=W1@bq+in_b[:32], [32:64) bk'=W2@bk, [64:96) bv'=W3@bv,
// [96:128) PWy, [128:160) PWx, [160:192) pb3=W3@pos_b
__global__ __launch_bounds__(256) void prep(const float* __restrict__ wq, const float* __restrict__ wk,
                          const float* __restrict__ wv, const float* __restrict__ in_w,
                          const float* __restrict__ out_w,
                          const float* __restrict__ bq, const float* __restrict__ bk,
                          const float* __restrict__ bv, const float* __restrict__ in_b,
                          const float* __restrict__ pos_w, const float* __restrict__ pos_b,
                          float* __restrict__ M, float* __restrict__ V, int* __restrict__ fmap_i) {
    int blk = blockIdx.x;
    if (blk < 16) {
        int tid = blk * 256 + threadIdx.x;   // 0..4095
        int which = tid >> 10;
        int e = tid & 1023;
        int cp = e & 31;
        int j  = e >> 5;
        if (which < 3) {
            const float* w = (which == 0) ? wq : ((which == 1) ? wk : wv);
            const float* Wrow = in_w + (which * 32 + cp) * 32;
            float acc = 0.f;
            #pragma unroll
            for (int t = 0; t < 32; ++t) acc += Wrow[t] * w[t * 32 + j];
            M[which * 1024 + j * 32 + cp] = acc;
        } else {
            M[3 * 1024 + j * 32 + cp] = out_w[cp * 32 + j];
        }
    } else if (blk == 16) {
        int tid = threadIdx.x;
        if (tid < 32) {
            float a = 0.f, b = 0.f, c = 0.f;
            #pragma unroll
            for (int t = 0; t < 32; ++t) {
                a += in_w[tid * 32 + t] * bq[t];
                b += in_w[(32 + tid) * 32 + t] * bk[t];
                c += in_w[(64 + tid) * 32 + t] * bv[t];
            }
            V[tid]      = a + in_b[tid];
            V[32 + tid] = b;
            V[64 + tid] = c;
        } else if (tid < 128) {
            int grp = (tid - 32) >> 5;   // 0=PWy 1=PWx 2=pb3
            int cp  = tid & 31;
            float acc = 0.f;
            #pragma unroll
            for (int t = 0; t < 32; ++t) {
                float src = (grp == 0) ? pos_w[t * 2 + 0] : ((grp == 1) ? pos_w[t * 2 + 1] : pos_b[t]);
                acc += in_w[(64 + cp) * 32 + t] * src;
            }
            V[96 + grp * 32 + cp] = acc;
        }
    } else {
        // blocks 17..80: zero the 512 KB flag map (131072 ints; 64 blocks x 256 thr x 8 ints)
        int base = (blk - 17) * 2048 + threadIdx.x * 8;
        int4 z = {0, 0, 0, 0};
        *(int4*)(fmap_i + base)     = z;
        *(int4*)(fmap_i + base + 4) = z;
    }
}

// ---------------- stage1: point-parallel LN + fused q/k/v linears (pixel-dense out) ----------------
// Coalesced feats/coors reads; writes q (64 B) + kv (128 B = 1 line) at pixel slots + flag byte.
__global__ __launch_bounds__(256) void stage1(const float* __restrict__ feats,
                                              const int* __restrict__ coors,
                                              const float* __restrict__ ln_w,
                                              const float* __restrict__ ln_b,
                                              const float* __restrict__ M,
                                              const float* __restrict__ V,
                                              __half* __restrict__ qh,
                                              __half* __restrict__ kvh,
                                              unsigned char* __restrict__ fmap) {
    int gp = blockIdx.x * 256 + threadIdx.x;
    if (gp >= NPTS) return;
    int b = (gp >= NN) ? 1 : 0;
    int2 yx = ((const int2*)coors)[gp];
    int pix = (b << 18) + (yx.x << 9) + yx.y;

    const float* fr = feats + ((size_t)gp << 5);
    float x[32];
    #pragma unroll
    for (int k = 0; k < 8; ++k) ((float4*)x)[k] = ((const float4*)fr)[k];

    float s1 = 0.f, s2 = 0.f;
    #pragma unroll
    for (int j = 0; j < 32; ++j) { s1 += x[j]; s2 += x[j] * x[j]; }
    float mu   = s1 * (1.f / 32.f);
    float var  = s2 * (1.f / 32.f) - mu * mu;
    float rstd = rsqrtf(var + 1e-5f);
    #pragma unroll
    for (int j = 0; j < 32; ++j) x[j] = (x[j] - mu) * rstd * ln_w[j] + ln_b[j];

    float acc[32];
    __half2 hbuf[16];

    // q' = x @ Mq + bq'  -> fp16 at pixel slot
    #pragma unroll
    for (int c = 0; c < 32; ++c) acc[c] = V[c];
    #pragma unroll
    for (int j = 0; j < 32; ++j) {
        float xv = x[j];
        #pragma unroll
        for (int c = 0; c < 32; ++c) acc[c] += xv * M[j * 32 + c];
    }
    #pragma unroll
    for (int c = 0; c < 16; ++c) hbuf[c] = __floats2half2_rn(acc[2 * c], acc[2 * c + 1]);
    {
        float4* qd = (float4*)(qh + ((size_t)pix << 5));
        #pragma unroll
        for (int k = 0; k < 4; ++k) qd[k] = ((float4*)hbuf)[k];
    }

    __half2 kvbuf[32];   // 128 B: k halves [0:16), v halves [16:32)

    // k' = x @ Mk + bk'  -> fp16
    #pragma unroll
    for (int c = 0; c < 32; ++c) acc[c] = V[32 + c];
    #pragma unroll
    for (int j = 0; j < 32; ++j) {
        float xv = x[j];
        #pragma unroll
        for (int c = 0; c < 32; ++c) acc[c] += xv * M[1024 + j * 32 + c];
    }
    #pragma unroll
    for (int c = 0; c < 16; ++c) kvbuf[c] = __floats2half2_rn(acc[2 * c], acc[2 * c + 1]);

    // v' = x @ Mv + bv'  -> fp16
    #pragma unroll
    for (int c = 0; c < 32; ++c) acc[c] = V[64 + c];
    #pragma unroll
    for (int j = 0; j < 32; ++j) {
        float xv = x[j];
        #pragma unroll
        for (int c = 0; c < 32; ++c) acc[c] += xv * M[2048 + j * 32 + c];
    }
    #pragma unroll
    for (int c = 0; c < 16; ++c) kvbuf[16 + c] = __floats2half2_rn(acc[2 * c], acc[2 * c + 1]);

    float4* kd = (float4*)(kvh + ((size_t)pix << 6));
    #pragma unroll
    for (int k = 0; k < 8; ++k) kd[k] = ((float4*)kvbuf)[k];

    fmap[pix] = 1;
}

// ---------------- stage23: fused attention + out-proj + canvas write ----------------
// Block = one 256-pixel window. Phase A runs TWO threads per occupied pixel (one per
// attention head): ~91% lane activity, per-thread chains halved. CRITICAL: the runtime
// head bit h feeds ONLY memory addresses (global/LDS offsets), never register-array
// indices — round-1's acc[runtime] indexing demoted registers to scratch (VGPR 256,
// 584 MB scratch writes). Out-proj is split by OUTPUT column: partner's o[16] arrives
// via 16 compile-time-indexed __shfl_xor, each thread computes its head's 16 columns.
__global__ __launch_bounds__(256) void stage23(const unsigned char* __restrict__ fmap,
                                               const __half* __restrict__ qh,
                                               const __half* __restrict__ kvh,
                                               const float* __restrict__ M,
                                               const float* __restrict__ V,
                                               const float* __restrict__ in_b,
                                               const float* __restrict__ out_b,
                                               float* __restrict__ out) {
    __shared__ __half2 lso[256 * 17];   // 17 half2 (68 B) stride per point
    __shared__ int lsp[256];
    __shared__ int woff[4];

    int w = (blockIdx.x & 7) * 256 + (blockIdx.x >> 3);   // XCD-swizzled window index
    int tid = threadIdx.x;
    int pix = w * 256 + tid;

    bool occ = fmap[pix] != 0;
    unsigned long long mask = __ballot(occ);
    int lane = tid & 63, wvi = tid >> 6;
    if (lane == 0) woff[wvi] = __popcll(mask);
    __syncthreads();
    int pre = 0;
    for (int ww = 0; ww < wvi; ++ww) pre += woff[ww];
    int cnt = woff[0] + woff[1] + woff[2] + woff[3];
    int slot = -1;
    if (occ) {
        slot = pre + __popcll(mask & ((1ull << lane) - 1ull));
        lsp[slot] = tid;
    }
    __syncthreads();

    const int DYC[9] = {0,-1,1,0,-1,1,0,-1,1};
    const int DXC[9] = {0,0,0,1,1,1,-1,-1,-1};

    // ---- phase A: attention, thread pair (point, head) ----
    for (int t = tid; t < 2 * cnt; t += 256) {
        int pt = t >> 1;          // point slot
        int h  = t & 1;           // head (memory offsets ONLY)
        int hb = h << 4;          // channel base of this head
        int pixl = w * 256 + lsp[pt];
        int b = pixl >> 18;
        int p = pixl & (HWPIX - 1);
        int y = p >> 9, x = p & 511;

        // this head's 16 q channels (32 B; pair lanes cover the full 64 B line)
        float qf[16];
        {
            const float4* q4 = (const float4*)(qh + ((size_t)pixl << 5)) + (h << 1);
            h8_to_f8(q4[0], qf); h8_to_f8(q4[1], qf + 8);
        }

        // 9 taps: validity is arithmetic + one independent flag byte each
        int np[9];
        bool nv[9];
        #pragma unroll
        for (int s = 0; s < 9; ++s) {
            int sy = y + DYC[s], sx = x + DXC[s];
            bool inb = (sy >= 0) & (sy < HH) & (sx >= 0) & (sx < WW);
            int npx = (b << 18) + (sy << 9) + sx;
            np[s] = npx;
            nv[s] = inb ? (fmap[npx] != 0) : false;
        }

        float eb = 0.f;
        #pragma unroll
        for (int c = 0; c < 16; ++c) eb += qf[c] * in_b[32 + hb + c];

        float lg[9];
        #pragma unroll
        for (int s = 0; s < 9; ++s) {
            float d = eb;
            if (nv[s]) {
                const float4* kp = (const float4*)(kvh + ((size_t)np[s] << 6)) + (h << 1);
                float kf[16];
                h8_to_f8(kp[0], kf); h8_to_f8(kp[1], kf + 8);
                #pragma unroll
                for (int c = 0; c < 16; ++c) d += qf[c] * kf[c];
            }
            lg[s] = d * 0.25f;   // 1/sqrt(HD=16)
        }
        float mx = lg[0];
        #pragma unroll
        for (int s = 1; s < 9; ++s) mx = fmaxf(mx, lg[s]);
        float lsum = 0.f;
        #pragma unroll
        for (int s = 0; s < 9; ++s) { lg[s] = __expf(lg[s] - mx); lsum += lg[s]; }

        float o[16];
        #pragma unroll
        for (int c = 0; c < 16; ++c) o[c] = 0.f;
        float wdy = 0.f, wdx = 0.f, woc = 0.f;
        #pragma unroll
        for (int s = 0; s < 9; ++s) {
            if (nv[s]) {
                float ws = lg[s];
                const float4* vp = (const float4*)(kvh + ((size_t)np[s] << 6)) + 4 + (h << 1);
                float vf[16];
                h8_to_f8(vp[0], vf); h8_to_f8(vp[1], vf + 8);
                #pragma unroll
                for (int c = 0; c < 16; ++c) o[c] += ws * vf[c];
                wdy += ws * (float)DYC[s]; wdx += ws * (float)DXC[s]; woc += ws;
            }
        }
        float rl = 1.f / lsum;
        #pragma unroll
        for (int c = 0; c < 16; ++c) {
            o[c] = (o[c] + wdy * V[96 + hb + c] + wdx * V[128 + hb + c] + woc * V[160 + hb + c]) * rl
                 + in_b[64 + hb + c];
        }

        // exchange per-head attention outputs with partner lane (compile-time indices!)
        // pair (t, t^1) is always complete and in-wave: 2*cnt is even, pairs share a lane pair.
        float oo[16];
        #pragma unroll
        for (int j = 0; j < 16; ++j) oo[j] = __shfl_xor(o[j], 1);

        // out projection, split by OUTPUT column: this thread computes final channels
        // [hb, hb+16). Row r=hb+j weight times own o[j]; row r=(hb^16)+j times partner oo[j].
        float acc[16];
        #pragma unroll
        for (int c = 0; c < 16; ++c) acc[c] = out_b[hb + c];
        #pragma unroll
        for (int j = 0; j < 16; ++j) {
            float a  = o[j];
            float bv = oo[j];
            const float* Mr0 = M + 3072 + (hb + j) * 32 + hb;
            const float* Mr1 = M + 3072 + ((hb ^ 16) + j) * 32 + hb;
            #pragma unroll
            for (int c = 0; c < 16; ++c) acc[c] += a * Mr0[c] + bv * Mr1[c];
        }

        __half2* lrow = lso + pt * 17 + (h << 3);
        #pragma unroll
        for (int i = 0; i < 8; ++i) lrow[i] = __floats2half2_rn(acc[2 * i], acc[2 * i + 1]);
    }
    __syncthreads();

    // ---- phase B: canvas write (all 256 threads; 256 B contiguous per wave-instr) ----
    int b = pix >> 18;
    int p = pix & (HWPIX - 1);
    float* outb = out + (size_t)b * CC * HWPIX + p;
    if (occ) {
        const __half2* lrow = lso + slot * 17;
        #pragma unroll
        for (int c2 = 0; c2 < 16; ++c2) {
            float2 f = __half22float2(lrow[c2]);
            outb[(2 * c2) * HWPIX]     = f.x;
            outb[(2 * c2 + 1) * HWPIX] = f.y;
        }
    } else {
        #pragma unroll
        for (int cc = 0; cc < 32; ++cc) outb[cc * HWPIX] = 0.f;
    }
}

extern "C" void kernel_launch(void* const* d_in, const int* in_sizes, int n_in,
                              void* d_out, int out_size, void* d_ws, size_t ws_size,
                              hipStream_t stream) {
    const float* feats = (const float*)d_in[0];
    const int*   coors = (const int*)d_in[1];
    const float* ln_w  = (const float*)d_in[2];
    const float* ln_b  = (const float*)d_in[3];
    const float* wq    = (const float*)d_in[4];
    const float* bq    = (const float*)d_in[5];
    const float* wk    = (const float*)d_in[6];
    const float* bk    = (const float*)d_in[7];
    const float* wv    = (const float*)d_in[8];
    const float* bv    = (const float*)d_in[9];
    const float* pos_w = (const float*)d_in[10];
    const float* pos_b = (const float*)d_in[11];
    const float* in_w  = (const float*)d_in[12];
    const float* in_b  = (const float*)d_in[13];
    const float* out_w = (const float*)d_in[14];
    const float* out_b = (const float*)d_in[15];

    // workspace layout (pixel-dense)
    float*  M    = (float*)d_ws;                                        // 4096
    float*  V    = M + 4096;                                            // 192
    __half* qh   = (__half*)(V + 192);                                  // NPIX*32 halves (33.5 MB)
    __half* kvh  = qh + (size_t)NPIX * 32;                              // NPIX*64 halves (67.1 MB)
    unsigned char* fmap = (unsigned char*)(kvh + (size_t)NPIX * 64);    // NPIX bytes (0.5 MB)
    size_t need = (4096 + 192) * 4 + (size_t)NPIX * 96 * 2 + (size_t)NPIX;
    if (ws_size < need) {
        fprintf(stderr, "kernel_launch: ws too small: %zu < %zu\n", ws_size, need);
        return;
    }

    prep<<<81, 256, 0, stream>>>(wq, wk, wv, in_w, out_w, bq, bk, bv, in_b, pos_w, pos_b,
                                 M, V, (int*)fmap);
    stage1<<<(NPTS + 255) / 256, 256, 0, stream>>>(feats, coors, ln_w, ln_b, M, V, qh, kvh, fmap);
    stage23<<<NBLK, 256, 0, stream>>>(fmap, qh, kvh, M, V, in_b, out_b, (float*)d_out);
}

// Round 3
// 260.907 us; speedup vs baseline: 2.0002x; 1.7160x over previous
//
#include <hip/hip_runtime.h>
#include <hip/hip_fp16.h>
#include <cstdio>
#include <cstdint>

#define HH 512
#define WW 512
#define CC 32
#define BB 2
#define NN 120000
#define HWPIX (HH*WW)
#define NPTS (BB*NN)          // 240000 occupied points
#define NPIX (BB*HWPIX)       // 524288 pixels (pixel-dense storage)
#define NBLK (NPIX/256)       // 2048 pixel windows

__device__ __forceinline__ void h8_to_f8(float4 raw, float* o) {
    const __half2* h = (const __half2*)&raw;
    #pragma unroll
    for (int i = 0; i < 4; ++i) {
        float2 f = __half22float2(h[i]);
        o[2 * i] = f.x; o[2 * i + 1] = f.y;
    }
}

// ---------------- prep: compose weights + vecs + zero flag map (one kernel) ----------------
// M layout (floats): [0:1024) MqT, [1024:2048) MkT, [2048:3072) MvT, [3072:4096) owT
// V layout (floats): [0:32) bq'=W1@bq+in_b[:32], [32:64) bk'=W2@bk, [64:96) bv'=W3@bv,
// [96:128) PWy, [128:160) PWx, [160:192) pb3=W3@pos_b
__global__ __launch_bounds__(256) void prep(const float* __restrict__ wq, const float* __restrict__ wk,
                          const float* __restrict__ wv, const float* __restrict__ in_w,
                          const float* __restrict__ out_w,
                          const float* __restrict__ bq, const float* __restrict__ bk,
                          const float* __restrict__ bv, const float* __restrict__ in_b,
                          const float* __restrict__ pos_w, const float* __restrict__ pos_b,
                          float* __restrict__ M, float* __restrict__ V, int* __restrict__ fmap_i) {
    int blk = blockIdx.x;
    if (blk < 16) {
        int tid = blk * 256 + threadIdx.x;   // 0..4095
        int which = tid >> 10;
        int e = tid & 1023;
        int cp = e & 31;
        int j  = e >> 5;
        if (which < 3) {
            const float* w = (which == 0) ? wq : ((which == 1) ? wk : wv);
            const float* Wrow = in_w + (which * 32 + cp) * 32;
            float acc = 0.f;
            #pragma unroll
            for (int t = 0; t < 32; ++t) acc += Wrow[t] * w[t * 32 + j];
            M[which * 1024 + j * 32 + cp] = acc;
        } else {
            M[3 * 1024 + j * 32 + cp] = out_w[cp * 32 + j];
        }
    } else if (blk == 16) {
        int tid = threadIdx.x;
        if (tid < 32) {
            float a = 0.f, b = 0.f, c = 0.f;
            #pragma unroll
            for (int t = 0; t < 32; ++t) {
                a += in_w[tid * 32 + t] * bq[t];
                b += in_w[(32 + tid) * 32 + t] * bk[t];
                c += in_w[(64 + tid) * 32 + t] * bv[t];
            }
            V[tid]      = a + in_b[tid];
            V[32 + tid] = b;
            V[64 + tid] = c;
        } else if (tid < 128) {
            int grp = (tid - 32) >> 5;   // 0=PWy 1=PWx 2=pb3
            int cp  = tid & 31;
            float acc = 0.f;
            #pragma unroll
            for (int t = 0; t < 32; ++t) {
                float src = (grp == 0) ? pos_w[t * 2 + 0] : ((grp == 1) ? pos_w[t * 2 + 1] : pos_b[t]);
                acc += in_w[(64 + cp) * 32 + t] * src;
            }
            V[96 + grp * 32 + cp] = acc;
        }
    } else {
        // blocks 17..80: zero the 512 KB flag map (131072 ints; 64 blocks x 256 thr x 8 ints)
        int base = (blk - 17) * 2048 + threadIdx.x * 8;
        int4 z = {0, 0, 0, 0};
        *(int4*)(fmap_i + base)     = z;
        *(int4*)(fmap_i + base + 4) = z;
    }
}

// ---------------- stage1: point-parallel LN + fused q/k/v linears (pixel-dense out) ----------------
// Coalesced feats/coors reads; writes q (64 B) + kv (128 B = 1 line) at pixel slots + flag byte.
__global__ __launch_bounds__(256) void stage1(const float* __restrict__ feats,
                                              const int* __restrict__ coors,
                                              const float* __restrict__ ln_w,
                                              const float* __restrict__ ln_b,
                                              const float* __restrict__ M,
                                              const float* __restrict__ V,
                                              __half* __restrict__ qh,
                                              __half* __restrict__ kvh,
                                              unsigned char* __restrict__ fmap) {
    int gp = blockIdx.x * 256 + threadIdx.x;
    if (gp >= NPTS) return;
    int b = (gp >= NN) ? 1 : 0;
    int2 yx = ((const int2*)coors)[gp];
    int pix = (b << 18) + (yx.x << 9) + yx.y;

    const float* fr = feats + ((size_t)gp << 5);
    float x[32];
    #pragma unroll
    for (int k = 0; k < 8; ++k) ((float4*)x)[k] = ((const float4*)fr)[k];

    float s1 = 0.f, s2 = 0.f;
    #pragma unroll
    for (int j = 0; j < 32; ++j) { s1 += x[j]; s2 += x[j] * x[j]; }
    float mu   = s1 * (1.f / 32.f);
    float var  = s2 * (1.f / 32.f) - mu * mu;
    float rstd = rsqrtf(var + 1e-5f);
    #pragma unroll
    for (int j = 0; j < 32; ++j) x[j] = (x[j] - mu) * rstd * ln_w[j] + ln_b[j];

    float acc[32];
    __half2 hbuf[16];

    // q' = x @ Mq + bq'  -> fp16 at pixel slot
    #pragma unroll
    for (int c = 0; c < 32; ++c) acc[c] = V[c];
    #pragma unroll
    for (int j = 0; j < 32; ++j) {
        float xv = x[j];
        #pragma unroll
        for (int c = 0; c < 32; ++c) acc[c] += xv * M[j * 32 + c];
    }
    #pragma unroll
    for (int c = 0; c < 16; ++c) hbuf[c] = __floats2half2_rn(acc[2 * c], acc[2 * c + 1]);
    {
        float4* qd = (float4*)(qh + ((size_t)pix << 5));
        #pragma unroll
        for (int k = 0; k < 4; ++k) qd[k] = ((float4*)hbuf)[k];
    }

    __half2 kvbuf[32];   // 128 B: k halves [0:16), v halves [16:32)

    // k' = x @ Mk + bk'  -> fp16
    #pragma unroll
    for (int c = 0; c < 32; ++c) acc[c] = V[32 + c];
    #pragma unroll
    for (int j = 0; j < 32; ++j) {
        float xv = x[j];
        #pragma unroll
        for (int c = 0; c < 32; ++c) acc[c] += xv * M[1024 + j * 32 + c];
    }
    #pragma unroll
    for (int c = 0; c < 16; ++c) kvbuf[c] = __floats2half2_rn(acc[2 * c], acc[2 * c + 1]);

    // v' = x @ Mv + bv'  -> fp16
    #pragma unroll
    for (int c = 0; c < 32; ++c) acc[c] = V[64 + c];
    #pragma unroll
    for (int j = 0; j < 32; ++j) {
        float xv = x[j];
        #pragma unroll
        for (int c = 0; c < 32; ++c) acc[c] += xv * M[2048 + j * 32 + c];
    }
    #pragma unroll
    for (int c = 0; c < 16; ++c) kvbuf[16 + c] = __floats2half2_rn(acc[2 * c], acc[2 * c + 1]);

    float4* kd = (float4*)(kvh + ((size_t)pix << 6));
    #pragma unroll
    for (int k = 0; k < 8; ++k) kd[k] = ((float4*)kvbuf)[k];

    fmap[pix] = 1;
}

// ---------------- stage23: fused attention + out-proj + canvas write ----------------
// Block = 512 threads = one 256-pixel window, TWO threads per occupied pixel (one per
// head). Phase A is STRAIGHT-LINE (if tid < 2*cnt) — round-1/2's <=2-iteration loop
// was unrolled/pipelined by the compiler, doubling live ranges -> VGPR 256 + scratch
// spill (484 MB writes). The runtime head bit h feeds ONLY memory addresses, never
// register-array indices (rule #20). Out-proj split by output column via 16
// compile-time __shfl_xor(.,1) exchanges.
__global__ __launch_bounds__(512) void stage23(const unsigned char* __restrict__ fmap,
                                               const __half* __restrict__ qh,
                                               const __half* __restrict__ kvh,
                                               const float* __restrict__ M,
                                               const float* __restrict__ V,
                                               const float* __restrict__ in_b,
                                               const float* __restrict__ out_b,
                                               float* __restrict__ out) {
    __shared__ __half2 lso[256 * 17];   // 17 half2 (68 B) stride per point slot
    __shared__ int lsp[256];            // slot -> pixel-in-window
    __shared__ int lsl[256];            // pixel-in-window -> slot (-1 if empty)
    __shared__ int woff[4];

    int w = (blockIdx.x & 7) * 256 + (blockIdx.x >> 3);   // XCD-swizzled window index
    int tid = threadIdx.x;

    bool occ = false;
    unsigned long long mask = 0;
    int lane = tid & 63, wvi = tid >> 6;
    if (tid < 256) {
        occ = fmap[w * 256 + tid] != 0;
        mask = __ballot(occ);
        if (lane == 0) woff[wvi] = __popcll(mask);
    }
    __syncthreads();
    int cnt = woff[0] + woff[1] + woff[2] + woff[3];
    if (tid < 256) {
        int pre = 0;
        for (int ww = 0; ww < wvi; ++ww) pre += woff[ww];
        int slot = -1;
        if (occ) {
            slot = pre + __popcll(mask & ((1ull << lane) - 1ull));
            lsp[slot] = tid;
        }
        lsl[tid] = slot;
    }
    __syncthreads();

    const int DYC[9] = {0,-1,1,0,-1,1,0,-1,1};
    const int DXC[9] = {0,0,0,1,1,1,-1,-1,-1};

    // ---- phase A: attention, one thread per (point, head); straight-line ----
    if (tid < 2 * cnt) {
        int pt = tid >> 1;        // point slot
        int h  = tid & 1;         // head (memory offsets ONLY)
        int hb = h << 4;          // channel base of this head
        int pixl = w * 256 + lsp[pt];
        int b = pixl >> 18;
        int p = pixl & (HWPIX - 1);
        int y = p >> 9, x = p & 511;

        // this head's 16 q channels (32 B; pair lanes cover the full 64 B line)
        float qf[16];
        {
            const float4* q4 = (const float4*)(qh + ((size_t)pixl << 5)) + (h << 1);
            h8_to_f8(q4[0], qf); h8_to_f8(q4[1], qf + 8);
        }

        // 9 taps: validity is arithmetic + one independent flag byte each
        int np[9];
        bool nv[9];
        #pragma unroll
        for (int s = 0; s < 9; ++s) {
            int sy = y + DYC[s], sx = x + DXC[s];
            bool inb = (sy >= 0) & (sy < HH) & (sx >= 0) & (sx < WW);
            int npx = (b << 18) + (sy << 9) + sx;
            np[s] = npx;
            nv[s] = inb ? (fmap[npx] != 0) : false;
        }

        float eb = 0.f;
        #pragma unroll
        for (int c = 0; c < 16; ++c) eb += qf[c] * in_b[32 + hb + c];

        float lg[9];
        #pragma unroll
        for (int s = 0; s < 9; ++s) {
            float d = eb;
            if (nv[s]) {
                const float4* kp = (const float4*)(kvh + ((size_t)np[s] << 6)) + (h << 1);
                float kf[16];
                h8_to_f8(kp[0], kf); h8_to_f8(kp[1], kf + 8);
                #pragma unroll
                for (int c = 0; c < 16; ++c) d += qf[c] * kf[c];
            }
            lg[s] = d * 0.25f;   // 1/sqrt(HD=16)
        }
        float mx = lg[0];
        #pragma unroll
        for (int s = 1; s < 9; ++s) mx = fmaxf(mx, lg[s]);
        float lsum = 0.f;
        #pragma unroll
        for (int s = 0; s < 9; ++s) { lg[s] = __expf(lg[s] - mx); lsum += lg[s]; }

        float o[16];
        #pragma unroll
        for (int c = 0; c < 16; ++c) o[c] = 0.f;
        float wdy = 0.f, wdx = 0.f, woc = 0.f;
        #pragma unroll
        for (int s = 0; s < 9; ++s) {
            if (nv[s]) {
                float ws = lg[s];
                const float4* vp = (const float4*)(kvh + ((size_t)np[s] << 6)) + 4 + (h << 1);
                float vf[16];
                h8_to_f8(vp[0], vf); h8_to_f8(vp[1], vf + 8);
                #pragma unroll
                for (int c = 0; c < 16; ++c) o[c] += ws * vf[c];
                wdy += ws * (float)DYC[s]; wdx += ws * (float)DXC[s]; woc += ws;
            }
        }
        float rl = 1.f / lsum;
        #pragma unroll
        for (int c = 0; c < 16; ++c) {
            o[c] = (o[c] + wdy * V[96 + hb + c] + wdx * V[128 + hb + c] + woc * V[160 + hb + c]) * rl
                 + in_b[64 + hb + c];
        }

        // exchange per-head attention outputs with partner lane (compile-time indices!)
        // pair (tid, tid^1) is complete and in-wave: 2*cnt is even.
        float oo[16];
        #pragma unroll
        for (int j = 0; j < 16; ++j) oo[j] = __shfl_xor(o[j], 1);

        // out projection, split by OUTPUT column: this thread computes final channels
        // [hb, hb+16). Row r=hb+j weight times own o[j]; row r=(hb^16)+j times partner oo[j].
        float acc[16];
        #pragma unroll
        for (int c = 0; c < 16; ++c) acc[c] = out_b[hb + c];
        #pragma unroll
        for (int j = 0; j < 16; ++j) {
            float a  = o[j];
            float bv = oo[j];
            const float* Mr0 = M + 3072 + (hb + j) * 32 + hb;
            const float* Mr1 = M + 3072 + ((hb ^ 16) + j) * 32 + hb;
            #pragma unroll
            for (int c = 0; c < 16; ++c) acc[c] += a * Mr0[c] + bv * Mr1[c];
        }

        __half2* lrow = lso + pt * 17 + (h << 3);
        #pragma unroll
        for (int i = 0; i < 8; ++i) lrow[i] = __floats2half2_rn(acc[2 * i], acc[2 * i + 1]);
    }
    __syncthreads();

    // ---- phase B: canvas write (512 threads; 16 channels each, two 128 B segs/instr) ----
    {
        int pw = tid >> 1;          // pixel within window
        int h  = tid & 1;           // channel half
        int pix = w * 256 + pw;
        int b = pix >> 18;
        int p = pix & (HWPIX - 1);
        float* outb = out + (size_t)b * CC * HWPIX + p;
        int sl = lsl[pw];
        if (sl >= 0) {
            const __half2* lrow = lso + sl * 17 + (h << 3);
            #pragma unroll
            for (int i = 0; i < 8; ++i) {
                float2 f = __half22float2(lrow[i]);
                outb[((h << 4) + 2 * i) * HWPIX]     = f.x;
                outb[((h << 4) + 2 * i + 1) * HWPIX] = f.y;
            }
        } else {
            #pragma unroll
            for (int i = 0; i < 16; ++i) outb[((h << 4) + i) * HWPIX] = 0.f;
        }
    }
}

extern "C" void kernel_launch(void* const* d_in, const int* in_sizes, int n_in,
                              void* d_out, int out_size, void* d_ws, size_t ws_size,
                              hipStream_t stream) {
    const float* feats = (const float*)d_in[0];
    const int*   coors = (const int*)d_in[1];
    const float* ln_w  = (const float*)d_in[2];
    const float* ln_b  = (const float*)d_in[3];
    const float* wq    = (const float*)d_in[4];
    const float* bq    = (const float*)d_in[5];
    const float* wk    = (const float*)d_in[6];
    const float* bk    = (const float*)d_in[7];
    const float* wv    = (const float*)d_in[8];
    const float* bv    = (const float*)d_in[9];
    const float* pos_w = (const float*)d_in[10];
    const float* pos_b = (const float*)d_in[11];
    const float* in_w  = (const float*)d_in[12];
    const float* in_b  = (const float*)d_in[13];
    const float* out_w = (const float*)d_in[14];
    const float* out_b = (const float*)d_in[15];

    // workspace layout (pixel-dense)
    float*  M    = (float*)d_ws;                                        // 4096
    float*  V    = M + 4096;                                            // 192
    __half* qh   = (__half*)(V + 192);                                  // NPIX*32 halves (33.5 MB)
    __half* kvh  = qh + (size_t)NPIX * 32;                              // NPIX*64 halves (67.1 MB)
    unsigned char* fmap = (unsigned char*)(kvh + (size_t)NPIX * 64);    // NPIX bytes (0.5 MB)
    size_t need = (4096 + 192) * 4 + (size_t)NPIX * 96 * 2 + (size_t)NPIX;
    if (ws_size < need) {
        fprintf(stderr, "kernel_launch: ws too small: %zu < %zu\n", ws_size, need);
        return;
    }

    prep<<<81, 256, 0, stream>>>(wq, wk, wv, in_w, out_w, bq, bk, bv, in_b, pos_w, pos_b,
                                 M, V, (int*)fmap);
    stage1<<<(NPTS + 255) / 256, 256, 0, stream>>>(feats, coors, ln_w, ln_b, M, V, qh, kvh, fmap);
    stage23<<<NBLK, 512, 0, stream>>>(fmap, qh, kvh, M, V, in_b, out_b, (float*)d_out);
}

// Round 4
// 256.266 us; speedup vs baseline: 2.0364x; 1.0181x over previous
//
#include <hip/hip_runtime.h>
#include <hip/hip_fp16.h>
#include <cstdio>
#include <cstdint>

#define HH 512
#define WW 512
#define CC 32
#define BB 2
#define NN 120000
#define HWPIX (HH*WW)
#define NPTS (BB*NN)          // 240000 occupied points
#define NPIX (BB*HWPIX)       // 524288 pixels (pixel-dense storage)
#define NBLK (NPIX/256)       // 2048 pixel windows

__device__ __forceinline__ void h8_to_f8(float4 raw, float* o) {
    const __half2* h = (const __half2*)&raw;
    #pragma unroll
    for (int i = 0; i < 4; ++i) {
        float2 f = __half22float2(h[i]);
        o[2 * i] = f.x; o[2 * i + 1] = f.y;
    }
}

// ---------------- prep: compose weights + vecs + fill gpmap with -1 ----------------
// M layout (floats): [0:1024) MqT, [1024:2048) MkT, [2048:3072) MvT, [3072:4096) owT
// V layout (floats): [0:32) bq'=W1@bq+in_b[:32], [32:64) bk'=W2@bk, [64:96) bv'=W3@bv,
// [96:128) PWy, [128:160) PWx, [160:192) pb3=W3@pos_b
__global__ __launch_bounds__(256) void prep(const float* __restrict__ wq, const float* __restrict__ wk,
                          const float* __restrict__ wv, const float* __restrict__ in_w,
                          const float* __restrict__ out_w,
                          const float* __restrict__ bq, const float* __restrict__ bk,
                          const float* __restrict__ bv, const float* __restrict__ in_b,
                          const float* __restrict__ pos_w, const float* __restrict__ pos_b,
                          float* __restrict__ M, float* __restrict__ V, int* __restrict__ gpmap) {
    int blk = blockIdx.x;
    if (blk < 16) {
        int tid = blk * 256 + threadIdx.x;   // 0..4095
        int which = tid >> 10;
        int e = tid & 1023;
        int cp = e & 31;
        int j  = e >> 5;
        if (which < 3) {
            const float* w = (which == 0) ? wq : ((which == 1) ? wk : wv);
            const float* Wrow = in_w + (which * 32 + cp) * 32;
            float acc = 0.f;
            #pragma unroll
            for (int t = 0; t < 32; ++t) acc += Wrow[t] * w[t * 32 + j];
            M[which * 1024 + j * 32 + cp] = acc;
        } else {
            M[3 * 1024 + j * 32 + cp] = out_w[cp * 32 + j];
        }
    } else if (blk == 16) {
        int tid = threadIdx.x;
        if (tid < 32) {
            float a = 0.f, b = 0.f, c = 0.f;
            #pragma unroll
            for (int t = 0; t < 32; ++t) {
                a += in_w[tid * 32 + t] * bq[t];
                b += in_w[(32 + tid) * 32 + t] * bk[t];
                c += in_w[(64 + tid) * 32 + t] * bv[t];
            }
            V[tid]      = a + in_b[tid];
            V[32 + tid] = b;
            V[64 + tid] = c;
        } else if (tid < 128) {
            int grp = (tid - 32) >> 5;   // 0=PWy 1=PWx 2=pb3
            int cp  = tid & 31;
            float acc = 0.f;
            #pragma unroll
            for (int t = 0; t < 32; ++t) {
                float src = (grp == 0) ? pos_w[t * 2 + 0] : ((grp == 1) ? pos_w[t * 2 + 1] : pos_b[t]);
                acc += in_w[(64 + cp) * 32 + t] * src;
            }
            V[96 + grp * 32 + cp] = acc;
        }
    } else {
        // blocks 17..80: fill the 2 MB gpmap with -1 (524288 ints; 64 blocks x 256 thr x 32 ints)
        int base = (blk - 17) * 8192 + threadIdx.x * 32;
        int4 m1 = {-1, -1, -1, -1};
        #pragma unroll
        for (int k = 0; k < 8; ++k) *(int4*)(gpmap + base + 4 * k) = m1;
    }
}

// ---------------- stage1: point-parallel LN + fused q/k/v linears ----------------
// q goes gp-indexed (coalesced write); kv pixel-dense (neighbors address it by pixel
// arithmetic); gpmap[pix] = gp for validity + canvas gather.
__global__ __launch_bounds__(256) void stage1(const float* __restrict__ feats,
                                              const int* __restrict__ coors,
                                              const float* __restrict__ ln_w,
                                              const float* __restrict__ ln_b,
                                              const float* __restrict__ M,
                                              const float* __restrict__ V,
                                              __half* __restrict__ qg,
                                              __half* __restrict__ kvh,
                                              int* __restrict__ gpmap) {
    int gp = blockIdx.x * 256 + threadIdx.x;
    if (gp >= NPTS) return;
    int b = (gp >= NN) ? 1 : 0;
    int2 yx = ((const int2*)coors)[gp];
    int pix = (b << 18) + (yx.x << 9) + yx.y;

    const float* fr = feats + ((size_t)gp << 5);
    float x[32];
    #pragma unroll
    for (int k = 0; k < 8; ++k) ((float4*)x)[k] = ((const float4*)fr)[k];

    float s1 = 0.f, s2 = 0.f;
    #pragma unroll
    for (int j = 0; j < 32; ++j) { s1 += x[j]; s2 += x[j] * x[j]; }
    float mu   = s1 * (1.f / 32.f);
    float var  = s2 * (1.f / 32.f) - mu * mu;
    float rstd = rsqrtf(var + 1e-5f);
    #pragma unroll
    for (int j = 0; j < 32; ++j) x[j] = (x[j] - mu) * rstd * ln_w[j] + ln_b[j];

    float acc[32];
    __half2 hbuf[16];

    // q' = x @ Mq + bq'  -> fp16, gp-indexed (coalesced)
    #pragma unroll
    for (int c = 0; c < 32; ++c) acc[c] = V[c];
    #pragma unroll
    for (int j = 0; j < 32; ++j) {
        float xv = x[j];
        #pragma unroll
        for (int c = 0; c < 32; ++c) acc[c] += xv * M[j * 32 + c];
    }
    #pragma unroll
    for (int c = 0; c < 16; ++c) hbuf[c] = __floats2half2_rn(acc[2 * c], acc[2 * c + 1]);
    {
        float4* qd = (float4*)(qg + ((size_t)gp << 5));
        #pragma unroll
        for (int k = 0; k < 4; ++k) qd[k] = ((float4*)hbuf)[k];
    }

    __half2 kvbuf[32];   // 128 B: k halves [0:16), v halves [16:32)

    // k' = x @ Mk + bk'  -> fp16
    #pragma unroll
    for (int c = 0; c < 32; ++c) acc[c] = V[32 + c];
    #pragma unroll
    for (int j = 0; j < 32; ++j) {
        float xv = x[j];
        #pragma unroll
        for (int c = 0; c < 32; ++c) acc[c] += xv * M[1024 + j * 32 + c];
    }
    #pragma unroll
    for (int c = 0; c < 16; ++c) kvbuf[c] = __floats2half2_rn(acc[2 * c], acc[2 * c + 1]);

    // v' = x @ Mv + bv'  -> fp16
    #pragma unroll
    for (int c = 0; c < 32; ++c) acc[c] = V[64 + c];
    #pragma unroll
    for (int j = 0; j < 32; ++j) {
        float xv = x[j];
        #pragma unroll
        for (int c = 0; c < 32; ++c) acc[c] += xv * M[2048 + j * 32 + c];
    }
    #pragma unroll
    for (int c = 0; c < 16; ++c) kvbuf[16 + c] = __floats2half2_rn(acc[2 * c], acc[2 * c + 1]);

    float4* kd = (float4*)(kvh + ((size_t)pix << 6));
    #pragma unroll
    for (int k = 0; k < 8; ++k) kd[k] = ((float4*)kvbuf)[k];

    gpmap[pix] = gp;
}

// ---------------- stage2: attention, point-parallel, thread = (point, head) ----------------
// No window blocks, no compaction: 480000 threads, 100% lane density. All loads are
// UNCONDITIONAL straight-line (gpmap at clamped coords; k/v with fallback address =
// own pixel, masked by nvf) so the compiler batches the 9 scattered loads per phase
// instead of serializing 18 branch bodies. Runtime head bit h feeds only memory
// addresses (rule #20). Out-proj column-split via compile-time __shfl_xor(.,1).
__global__ __launch_bounds__(256) void stage2(const int* __restrict__ gpmap,
                                              const int* __restrict__ coors,
                                              const __half* __restrict__ qg,
                                              const __half* __restrict__ kvh,
                                              const float* __restrict__ M,
                                              const float* __restrict__ V,
                                              const float* __restrict__ in_b,
                                              const float* __restrict__ out_b,
                                              __half* __restrict__ obuf) {
    const int DYC[9] = {0,-1,1,0,-1,1,0,-1,1};
    const int DXC[9] = {0,0,0,1,1,1,-1,-1,-1};

    int t  = blockIdx.x * 256 + threadIdx.x;   // 0..479999 (exact grid)
    int gp = t >> 1;
    int h  = t & 1;          // head: memory offsets ONLY
    int hb = h << 4;
    int b  = (gp >= NN) ? 1 : 0;
    int2 yx = ((const int2*)coors)[gp];
    int y = yx.x, x = yx.y;
    int pix = (b << 18) + (y << 9) + x;

    // own q half (gp-indexed: wave reads 2 KB contiguous)
    float qf[16];
    {
        const float4* q4 = (const float4*)(qg + ((size_t)gp << 5)) + (h << 1);
        h8_to_f8(q4[0], qf); h8_to_f8(q4[1], qf + 8);
    }

    // 9 taps: gpmap at CLAMPED coords -> 9 unconditional scattered 4 B loads (batched)
    int np[9];
    float nvf[9];
    #pragma unroll
    for (int s = 0; s < 9; ++s) {
        int sy = y + DYC[s], sx = x + DXC[s];
        bool inb = (sy >= 0) & (sy < HH) & (sx >= 0) & (sx < WW);
        int syc = min(max(sy, 0), HH - 1);
        int sxc = min(max(sx, 0), WW - 1);
        int npx = (b << 18) + (syc << 9) + sxc;
        bool v = inb & (gpmap[npx] >= 0);
        np[s]  = v ? npx : pix;    // fallback: own pixel (always written, finite)
        nvf[s] = v ? 1.f : 0.f;
    }

    float eb = 0.f;
    #pragma unroll
    for (int c = 0; c < 16; ++c) eb += qf[c] * in_b[32 + hb + c];

    // 9 unconditional k loads (32 B each; pair lanes cover the 64 B k region)
    float lg[9];
    #pragma unroll
    for (int s = 0; s < 9; ++s) {
        const float4* kp = (const float4*)(kvh + ((size_t)np[s] << 6)) + (h << 1);
        float kf[16];
        h8_to_f8(kp[0], kf); h8_to_f8(kp[1], kf + 8);
        float d = 0.f;
        #pragma unroll
        for (int c = 0; c < 16; ++c) d += qf[c] * kf[c];
        lg[s] = (eb + d * nvf[s]) * 0.25f;   // 1/sqrt(HD=16); invalid tap -> eb
    }
    float mx = lg[0];
    #pragma unroll
    for (int s = 1; s < 9; ++s) mx = fmaxf(mx, lg[s]);
    float lsum = 0.f;
    #pragma unroll
    for (int s = 0; s < 9; ++s) { lg[s] = __expf(lg[s] - mx); lsum += lg[s]; }

    // 9 unconditional v loads, masked accumulate
    float o[16];
    #pragma unroll
    for (int c = 0; c < 16; ++c) o[c] = 0.f;
    float wdy = 0.f, wdx = 0.f, woc = 0.f;
    #pragma unroll
    for (int s = 0; s < 9; ++s) {
        const float4* vp = (const float4*)(kvh + ((size_t)np[s] << 6)) + 4 + (h << 1);
        float vf[16];
        h8_to_f8(vp[0], vf); h8_to_f8(vp[1], vf + 8);
        float wm = lg[s] * nvf[s];
        #pragma unroll
        for (int c = 0; c < 16; ++c) o[c] += wm * vf[c];
        wdy += wm * (float)DYC[s]; wdx += wm * (float)DXC[s]; woc += wm;
    }
    float rl = 1.f / lsum;
    #pragma unroll
    for (int c = 0; c < 16; ++c) {
        o[c] = (o[c] + wdy * V[96 + hb + c] + wdx * V[128 + hb + c] + woc * V[160 + hb + c]) * rl
             + in_b[64 + hb + c];
    }

    // partner exchange (compile-time indices; pair (t, t^1) always complete & in-wave)
    float oo[16];
    #pragma unroll
    for (int j = 0; j < 16; ++j) oo[j] = __shfl_xor(o[j], 1);

    // out-proj columns [hb, hb+16): own o -> rows hb+j, partner oo -> rows (hb^16)+j
    float acc[16];
    #pragma unroll
    for (int c = 0; c < 16; ++c) acc[c] = out_b[hb + c];
    #pragma unroll
    for (int j = 0; j < 16; ++j) {
        float a  = o[j];
        float bb = oo[j];
        const float* Mr0 = M + 3072 + (hb + j) * 32 + hb;
        const float* Mr1 = M + 3072 + ((hb ^ 16) + j) * 32 + hb;
        #pragma unroll
        for (int c = 0; c < 16; ++c) acc[c] += a * Mr0[c] + bb * Mr1[c];
    }

    // gp-indexed fp16 output: pair writes 64 B contiguous -> fully coalesced stream
    __half2 hb8[8];
    #pragma unroll
    for (int i = 0; i < 8; ++i) hb8[i] = __floats2half2_rn(acc[2 * i], acc[2 * i + 1]);
    float4* od = (float4*)(obuf + ((size_t)gp << 5)) + (h << 1);
    od[0] = ((float4*)hb8)[0];
    od[1] = ((float4*)hb8)[1];
}

// ---------------- stage3: canvas write (pure BW) ----------------
// Thread per pixel: gpmap coalesced; occupied -> gather 64 B from obuf (15 MB,
// L2/L3-resident) and write 32 floats strided-coalesced; else zeros.
__global__ __launch_bounds__(256) void stage3(const int* __restrict__ gpmap,
                                              const __half* __restrict__ obuf,
                                              float* __restrict__ out) {
    int pix = blockIdx.x * 256 + threadIdx.x;
    int b = pix >> 18;
    int p = pix & (HWPIX - 1);
    float* outb = out + (size_t)b * CC * HWPIX + p;
    int gp = gpmap[pix];
    if (gp >= 0) {
        const float4* o4 = (const float4*)(obuf + ((size_t)gp << 5));
        float4 r0 = o4[0], r1 = o4[1], r2 = o4[2], r3 = o4[3];
        float of[32];
        h8_to_f8(r0, of); h8_to_f8(r1, of + 8); h8_to_f8(r2, of + 16); h8_to_f8(r3, of + 24);
        #pragma unroll
        for (int c = 0; c < 32; ++c) outb[c * HWPIX] = of[c];
    } else {
        #pragma unroll
        for (int c = 0; c < 32; ++c) outb[c * HWPIX] = 0.f;
    }
}

extern "C" void kernel_launch(void* const* d_in, const int* in_sizes, int n_in,
                              void* d_out, int out_size, void* d_ws, size_t ws_size,
                              hipStream_t stream) {
    const float* feats = (const float*)d_in[0];
    const int*   coors = (const int*)d_in[1];
    const float* ln_w  = (const float*)d_in[2];
    const float* ln_b  = (const float*)d_in[3];
    const float* wq    = (const float*)d_in[4];
    const float* bq    = (const float*)d_in[5];
    const float* wk    = (const float*)d_in[6];
    const float* bk    = (const float*)d_in[7];
    const float* wv    = (const float*)d_in[8];
    const float* bv    = (const float*)d_in[9];
    const float* pos_w = (const float*)d_in[10];
    const float* pos_b = (const float*)d_in[11];
    const float* in_w  = (const float*)d_in[12];
    const float* in_b  = (const float*)d_in[13];
    const float* out_w = (const float*)d_in[14];
    const float* out_b = (const float*)d_in[15];

    // workspace layout
    float*  M    = (float*)d_ws;                                        // 4096 floats
    float*  V    = M + 4096;                                            // 192 floats
    __half* qg   = (__half*)(V + 192);                                  // NPTS*32 halves (15.4 MB, gp-indexed)
    __half* kvh  = qg + (size_t)NPTS * 32;                              // NPIX*64 halves (67.1 MB, pixel-dense)
    __half* obuf = kvh + (size_t)NPIX * 64;                             // NPTS*32 halves (15.4 MB, gp-indexed)
    int*   gpmap = (int*)(obuf + (size_t)NPTS * 32);                    // NPIX ints (2 MB)
    size_t need = (4096 + 192) * 4 + (size_t)NPTS * 64 * 2 + (size_t)NPIX * 128 + (size_t)NPIX * 4;
    if (ws_size < need) {
        fprintf(stderr, "kernel_launch: ws too small: %zu < %zu\n", ws_size, need);
        return;
    }

    prep<<<81, 256, 0, stream>>>(wq, wk, wv, in_w, out_w, bq, bk, bv, in_b, pos_w, pos_b,
                                 M, V, gpmap);
    stage1<<<(NPTS + 255) / 256, 256, 0, stream>>>(feats, coors, ln_w, ln_b, M, V, qg, kvh, gpmap);
    stage2<<<(NPTS * 2) / 256, 256, 0, stream>>>(gpmap, coors, qg, kvh, M, V, in_b, out_b, obuf);
    stage3<<<NBLK, 256, 0, stream>>>(gpmap, obuf, (float*)d_out);
}

// Round 5
// 223.344 us; speedup vs baseline: 2.3366x; 1.1474x over previous
//
#include <hip/hip_runtime.h>
#include <hip/hip_fp16.h>
#include <cstdio>
#include <cstdint>

#define HH 512
#define WW 512
#define CC 32
#define BB 2
#define NN 120000
#define HWPIX (HH*WW)
#define NPTS (BB*NN)          // 240000 occupied points
#define NPIX (BB*HWPIX)       // 524288 pixels (pixel-dense storage)
#define WPIX 128              // pixels per stage23 window
#define NBLK2 (NPIX/WPIX)     // 4096 windows

__device__ __forceinline__ void h8_to_f8(float4 raw, float* o) {
    const __half2* h = (const __half2*)&raw;
    #pragma unroll
    for (int i = 0; i < 4; ++i) {
        float2 f = __half22float2(h[i]);
        o[2 * i] = f.x; o[2 * i + 1] = f.y;
    }
}

// ---------------- prep: compose weights + vecs + zero flag map (one kernel) ----------------
// M layout (floats): [0:1024) MqT, [1024:2048) MkT, [2048:3072) MvT, [3072:4096) owT
// V layout (floats): [0:32) bq'=W1@bq+in_b[:32], [32:64) bk'=W2@bk, [64:96) bv'=W3@bv,
// [96:128) PWy, [128:160) PWx, [160:192) pb3=W3@pos_b
__global__ __launch_bounds__(256) void prep(const float* __restrict__ wq, const float* __restrict__ wk,
                          const float* __restrict__ wv, const float* __restrict__ in_w,
                          const float* __restrict__ out_w,
                          const float* __restrict__ bq, const float* __restrict__ bk,
                          const float* __restrict__ bv, const float* __restrict__ in_b,
                          const float* __restrict__ pos_w, const float* __restrict__ pos_b,
                          float* __restrict__ M, float* __restrict__ V, int* __restrict__ fmap_i) {
    int blk = blockIdx.x;
    if (blk < 16) {
        int tid = blk * 256 + threadIdx.x;   // 0..4095
        int which = tid >> 10;
        int e = tid & 1023;
        int cp = e & 31;
        int j  = e >> 5;
        if (which < 3) {
            const float* w = (which == 0) ? wq : ((which == 1) ? wk : wv);
            const float* Wrow = in_w + (which * 32 + cp) * 32;
            float acc = 0.f;
            #pragma unroll
            for (int t = 0; t < 32; ++t) acc += Wrow[t] * w[t * 32 + j];
            M[which * 1024 + j * 32 + cp] = acc;
        } else {
            M[3 * 1024 + j * 32 + cp] = out_w[cp * 32 + j];
        }
    } else if (blk == 16) {
        int tid = threadIdx.x;
        if (tid < 32) {
            float a = 0.f, b = 0.f, c = 0.f;
            #pragma unroll
            for (int t = 0; t < 32; ++t) {
                a += in_w[tid * 32 + t] * bq[t];
                b += in_w[(32 + tid) * 32 + t] * bk[t];
                c += in_w[(64 + tid) * 32 + t] * bv[t];
            }
            V[tid]      = a + in_b[tid];
            V[32 + tid] = b;
            V[64 + tid] = c;
        } else if (tid < 128) {
            int grp = (tid - 32) >> 5;   // 0=PWy 1=PWx 2=pb3
            int cp  = tid & 31;
            float acc = 0.f;
            #pragma unroll
            for (int t = 0; t < 32; ++t) {
                float src = (grp == 0) ? pos_w[t * 2 + 0] : ((grp == 1) ? pos_w[t * 2 + 1] : pos_b[t]);
                acc += in_w[(64 + cp) * 32 + t] * src;
            }
            V[96 + grp * 32 + cp] = acc;
        }
    } else {
        // blocks 17..80: zero the 512 KB flag map (131072 ints; 64 blocks x 256 thr x 8 ints)
        int base = (blk - 17) * 2048 + threadIdx.x * 8;
        int4 z = {0, 0, 0, 0};
        *(int4*)(fmap_i + base)     = z;
        *(int4*)(fmap_i + base + 4) = z;
    }
}

// ---------------- stage1: point-parallel LN + fused q/k/v linears (pixel-dense out) ----------------
// Coalesced feats/coors reads; writes q (64 B) + kv (128 B = 1 line) at pixel slots + flag byte.
__global__ __launch_bounds__(256) void stage1(const float* __restrict__ feats,
                                              const int* __restrict__ coors,
                                              const float* __restrict__ ln_w,
                                              const float* __restrict__ ln_b,
                                              const float* __restrict__ M,
                                              const float* __restrict__ V,
                                              __half* __restrict__ qh,
                                              __half* __restrict__ kvh,
                                              unsigned char* __restrict__ fmap) {
    int gp = blockIdx.x * 256 + threadIdx.x;
    if (gp >= NPTS) return;
    int b = (gp >= NN) ? 1 : 0;
    int2 yx = ((const int2*)coors)[gp];
    int pix = (b << 18) + (yx.x << 9) + yx.y;

    const float* fr = feats + ((size_t)gp << 5);
    float x[32];
    #pragma unroll
    for (int k = 0; k < 8; ++k) ((float4*)x)[k] = ((const float4*)fr)[k];

    float s1 = 0.f, s2 = 0.f;
    #pragma unroll
    for (int j = 0; j < 32; ++j) { s1 += x[j]; s2 += x[j] * x[j]; }
    float mu   = s1 * (1.f / 32.f);
    float var  = s2 * (1.f / 32.f) - mu * mu;
    float rstd = rsqrtf(var + 1e-5f);
    #pragma unroll
    for (int j = 0; j < 32; ++j) x[j] = (x[j] - mu) * rstd * ln_w[j] + ln_b[j];

    float acc[32];
    __half2 hbuf[16];

    // q' = x @ Mq + bq'  -> fp16 at pixel slot
    #pragma unroll
    for (int c = 0; c < 32; ++c) acc[c] = V[c];
    #pragma unroll
    for (int j = 0; j < 32; ++j) {
        float xv = x[j];
        #pragma unroll
        for (int c = 0; c < 32; ++c) acc[c] += xv * M[j * 32 + c];
    }
    #pragma unroll
    for (int c = 0; c < 16; ++c) hbuf[c] = __floats2half2_rn(acc[2 * c], acc[2 * c + 1]);
    {
        float4* qd = (float4*)(qh + ((size_t)pix << 5));
        #pragma unroll
        for (int k = 0; k < 4; ++k) qd[k] = ((float4*)hbuf)[k];
    }

    __half2 kvbuf[32];   // 128 B: k halves [0:16), v halves [16:32)

    // k' = x @ Mk + bk'  -> fp16
    #pragma unroll
    for (int c = 0; c < 32; ++c) acc[c] = V[32 + c];
    #pragma unroll
    for (int j = 0; j < 32; ++j) {
        float xv = x[j];
        #pragma unroll
        for (int c = 0; c < 32; ++c) acc[c] += xv * M[1024 + j * 32 + c];
    }
    #pragma unroll
    for (int c = 0; c < 16; ++c) kvbuf[c] = __floats2half2_rn(acc[2 * c], acc[2 * c + 1]);

    // v' = x @ Mv + bv'  -> fp16
    #pragma unroll
    for (int c = 0; c < 32; ++c) acc[c] = V[64 + c];
    #pragma unroll
    for (int j = 0; j < 32; ++j) {
        float xv = x[j];
        #pragma unroll
        for (int c = 0; c < 32; ++c) acc[c] += xv * M[2048 + j * 32 + c];
    }
    #pragma unroll
    for (int c = 0; c < 16; ++c) kvbuf[16 + c] = __floats2half2_rn(acc[2 * c], acc[2 * c + 1]);

    float4* kd = (float4*)(kvh + ((size_t)pix << 6));
    #pragma unroll
    for (int k = 0; k < 8; ++k) kd[k] = ((float4*)kvbuf)[k];

    fmap[pix] = 1;
}

// ---------------- stage23: fused attention + out-proj + canvas write ----------------
// Block = 256 threads = one 128-pixel window, TWO threads per occupied pixel (one per
// head). Straight-line phase A (r3 lesson: tiny loops get unrolled -> spill); runtime
// head bit h feeds only memory addresses (r1 lesson: never register-array indices);
// k/v loads UNCONDITIONAL at clamped/fallback addresses masked by nvf (r4 lesson:
// branch-gated scattered loads serialize ~18 latency exposures); 128-px windows keep
// kv reads L2-local (r0: FETCH 27 MB vs r4's point-parallel 83 MB).
__global__ __launch_bounds__(256) void stage23(const unsigned char* __restrict__ fmap,
                                               const __half* __restrict__ qh,
                                               const __half* __restrict__ kvh,
                                               const float* __restrict__ M,
                                               const float* __restrict__ V,
                                               const float* __restrict__ in_b,
                                               const float* __restrict__ out_b,
                                               float* __restrict__ out) {
    __shared__ __half2 lso[WPIX * 17];  // 17 half2 (68 B) stride per point slot
    __shared__ int lsp[WPIX];           // slot -> pixel-in-window
    __shared__ int lsl[WPIX];           // pixel-in-window -> slot (-1 if empty)
    __shared__ int woff[2];

    int w = (blockIdx.x & 7) * (NBLK2 / 8) + (blockIdx.x >> 3);   // XCD-swizzled window
    int tid = threadIdx.x;

    if (tid < WPIX) {
        bool occ = fmap[w * WPIX + tid] != 0;
        unsigned long long mask = __ballot(occ);
        int lane = tid & 63, wvi = tid >> 6;
        if (lane == 0) woff[wvi] = __popcll(mask);
        __syncthreads();
        int pre = (wvi == 1) ? woff[0] : 0;
        int slot = -1;
        if (occ) {
            slot = pre + __popcll(mask & ((1ull << lane) - 1ull));
            lsp[slot] = tid;
        }
        lsl[tid] = slot;
    } else {
        __syncthreads();
    }
    __syncthreads();
    int cnt = woff[0] + woff[1];

    const int DYC[9] = {0,-1,1,0,-1,1,0,-1,1};
    const int DXC[9] = {0,0,0,1,1,1,-1,-1,-1};

    // ---- phase A: one thread per (point, head); straight-line ----
    if (tid < 2 * cnt) {
        int pt = tid >> 1;        // point slot
        int h  = tid & 1;         // head (memory offsets ONLY)
        int hb = h << 4;          // channel base of this head
        int pixl = w * WPIX + lsp[pt];
        int b = pixl >> 18;
        int p = pixl & (HWPIX - 1);
        int y = p >> 9, x = p & 511;

        // this head's 16 q channels (32 B; pair lanes cover the full 64 B line)
        float qf[16];
        {
            const float4* q4 = (const float4*)(qh + ((size_t)pixl << 5)) + (h << 1);
            h8_to_f8(q4[0], qf); h8_to_f8(q4[1], qf + 8);
        }

        // 9 taps: clamped coords -> 9 unconditional flag loads (batched); fallback = own pixel
        int np[9];
        float nvf[9];
        #pragma unroll
        for (int s = 0; s < 9; ++s) {
            int sy = y + DYC[s], sx = x + DXC[s];
            bool inb = (sy >= 0) & (sy < HH) & (sx >= 0) & (sx < WW);
            int syc = min(max(sy, 0), HH - 1);
            int sxc = min(max(sx, 0), WW - 1);
            int npx = (b << 18) + (syc << 9) + sxc;
            bool v = inb & (fmap[npx] != 0);
            np[s]  = v ? npx : pixl;
            nvf[s] = v ? 1.f : 0.f;
        }

        float eb = 0.f;
        #pragma unroll
        for (int c = 0; c < 16; ++c) eb += qf[c] * in_b[32 + hb + c];

        // 9 unconditional k loads (32 B each), masked dot
        float lg[9];
        #pragma unroll
        for (int s = 0; s < 9; ++s) {
            const float4* kp = (const float4*)(kvh + ((size_t)np[s] << 6)) + (h << 1);
            float kf[16];
            h8_to_f8(kp[0], kf); h8_to_f8(kp[1], kf + 8);
            float d = 0.f;
            #pragma unroll
            for (int c = 0; c < 16; ++c) d += qf[c] * kf[c];
            lg[s] = (eb + d * nvf[s]) * 0.25f;   // 1/sqrt(HD=16); invalid tap -> eb
        }
        float mx = lg[0];
        #pragma unroll
        for (int s = 1; s < 9; ++s) mx = fmaxf(mx, lg[s]);
        float lsum = 0.f;
        #pragma unroll
        for (int s = 0; s < 9; ++s) { lg[s] = __expf(lg[s] - mx); lsum += lg[s]; }

        // 9 unconditional v loads, masked accumulate
        float o[16];
        #pragma unroll
        for (int c = 0; c < 16; ++c) o[c] = 0.f;
        float wdy = 0.f, wdx = 0.f, woc = 0.f;
        #pragma unroll
        for (int s = 0; s < 9; ++s) {
            const float4* vp = (const float4*)(kvh + ((size_t)np[s] << 6)) + 4 + (h << 1);
            float vf[16];
            h8_to_f8(vp[0], vf); h8_to_f8(vp[1], vf + 8);
            float wm = lg[s] * nvf[s];
            #pragma unroll
            for (int c = 0; c < 16; ++c) o[c] += wm * vf[c];
            wdy += wm * (float)DYC[s]; wdx += wm * (float)DXC[s]; woc += wm;
        }
        float rl = 1.f / lsum;
        #pragma unroll
        for (int c = 0; c < 16; ++c) {
            o[c] = (o[c] + wdy * V[96 + hb + c] + wdx * V[128 + hb + c] + woc * V[160 + hb + c]) * rl
                 + in_b[64 + hb + c];
        }

        // partner exchange (compile-time indices; pair (tid, tid^1) complete & in-wave)
        float oo[16];
        #pragma unroll
        for (int j = 0; j < 16; ++j) oo[j] = __shfl_xor(o[j], 1);

        // out-proj columns [hb, hb+16): own o -> rows hb+j, partner oo -> rows (hb^16)+j
        float acc[16];
        #pragma unroll
        for (int c = 0; c < 16; ++c) acc[c] = out_b[hb + c];
        #pragma unroll
        for (int j = 0; j < 16; ++j) {
            float a  = o[j];
            float bb = oo[j];
            const float* Mr0 = M + 3072 + (hb + j) * 32 + hb;
            const float* Mr1 = M + 3072 + ((hb ^ 16) + j) * 32 + hb;
            #pragma unroll
            for (int c = 0; c < 16; ++c) acc[c] += a * Mr0[c] + bb * Mr1[c];
        }

        __half2* lrow = lso + pt * 17 + (h << 3);
        #pragma unroll
        for (int i = 0; i < 8; ++i) lrow[i] = __floats2half2_rn(acc[2 * i], acc[2 * i + 1]);
    }
    __syncthreads();

    // ---- phase B: canvas write (256 threads; 128 px x 2 halves; 16 ch each) ----
    {
        int pw = tid >> 1;          // pixel within window
        int h  = tid & 1;           // channel half
        int pix = w * WPIX + pw;
        int b = pix >> 18;
        int p = pix & (HWPIX - 1);
        float* outb = out + (size_t)b * CC * HWPIX + p;
        int sl = lsl[pw];
        if (sl >= 0) {
            const __half2* lrow = lso + sl * 17 + (h << 3);
            #pragma unroll
            for (int i = 0; i < 8; ++i) {
                float2 f = __half22float2(lrow[i]);
                outb[((h << 4) + 2 * i) * HWPIX]     = f.x;
                outb[((h << 4) + 2 * i + 1) * HWPIX] = f.y;
            }
        } else {
            #pragma unroll
            for (int i = 0; i < 16; ++i) outb[((h << 4) + i) * HWPIX] = 0.f;
        }
    }
}

extern "C" void kernel_launch(void* const* d_in, const int* in_sizes, int n_in,
                              void* d_out, int out_size, void* d_ws, size_t ws_size,
                              hipStream_t stream) {
    const float* feats = (const float*)d_in[0];
    const int*   coors = (const int*)d_in[1];
    const float* ln_w  = (const float*)d_in[2];
    const float* ln_b  = (const float*)d_in[3];
    const float* wq    = (const float*)d_in[4];
    const float* bq    = (const float*)d_in[5];
    const float* wk    = (const float*)d_in[6];
    const float* bk    = (const float*)d_in[7];
    const float* wv    = (const float*)d_in[8];
    const float* bv    = (const float*)d_in[9];
    const float* pos_w = (const float*)d_in[10];
    const float* pos_b = (const float*)d_in[11];
    const float* in_w  = (const float*)d_in[12];
    const float* in_b  = (const float*)d_in[13];
    const float* out_w = (const float*)d_in[14];
    const float* out_b = (const float*)d_in[15];

    // workspace layout (pixel-dense)
    float*  M    = (float*)d_ws;                                        // 4096
    float*  V    = M + 4096;                                            // 192
    __half* qh   = (__half*)(V + 192);                                  // NPIX*32 halves (33.5 MB)
    __half* kvh  = qh + (size_t)NPIX * 32;                              // NPIX*64 halves (67.1 MB)
    unsigned char* fmap = (unsigned char*)(kvh + (size_t)NPIX * 64);    // NPIX bytes (0.5 MB)
    size_t need = (4096 + 192) * 4 + (size_t)NPIX * 96 * 2 + (size_t)NPIX;
    if (ws_size < need) {
        fprintf(stderr, "kernel_launch: ws too small: %zu < %zu\n", ws_size, need);
        return;
    }

    prep<<<81, 256, 0, stream>>>(wq, wk, wv, in_w, out_w, bq, bk, bv, in_b, pos_w, pos_b,
                                 M, V, (int*)fmap);
    stage1<<<(NPTS + 255) / 256, 256, 0, stream>>>(feats, coors, ln_w, ln_b, M, V, qh, kvh, fmap);
    stage23<<<NBLK2, 256, 0, stream>>>(fmap, qh, kvh, M, V, in_b, out_b, (float*)d_out);
}

// Round 6
// 192.572 us; speedup vs baseline: 2.7099x; 1.1598x over previous
//
#include <hip/hip_runtime.h>
#include <hip/hip_fp16.h>
#include <cstdio>
#include <cstdint>

#define HH 512
#define WW 512
#define CC 32
#define BB 2
#define NN 120000
#define HWPIX (HH*WW)
#define NPTS (BB*NN)          // 240000 occupied points
#define NPIX (BB*HWPIX)       // 524288 pixels (pixel-dense storage)
#define NBLK (NPIX/256)       // 2048 pixel windows

__device__ __forceinline__ void h8_to_f8(float4 raw, float* o) {
    const __half2* h = (const __half2*)&raw;
    #pragma unroll
    for (int i = 0; i < 4; ++i) {
        float2 f = __half22float2(h[i]);
        o[2 * i] = f.x; o[2 * i + 1] = f.y;
    }
}

// ---------------- prep: compose weights + vecs + zero flag map (one kernel) ----------------
// M layout (floats): [0:1024) MqT, [1024:2048) MkT, [2048:3072) MvT, [3072:4096) owT
// V layout (floats): [0:32) bq'=W1@bq+in_b[:32], [32:64) bk'=W2@bk, [64:96) bv'=W3@bv,
// [96:128) PWy, [128:160) PWx, [160:192) pb3=W3@pos_b
__global__ __launch_bounds__(256) void prep(const float* __restrict__ wq, const float* __restrict__ wk,
                          const float* __restrict__ wv, const float* __restrict__ in_w,
                          const float* __restrict__ out_w,
                          const float* __restrict__ bq, const float* __restrict__ bk,
                          const float* __restrict__ bv, const float* __restrict__ in_b,
                          const float* __restrict__ pos_w, const float* __restrict__ pos_b,
                          float* __restrict__ M, float* __restrict__ V, int* __restrict__ fmap_i) {
    int blk = blockIdx.x;
    if (blk < 16) {
        int tid = blk * 256 + threadIdx.x;   // 0..4095
        int which = tid >> 10;
        int e = tid & 1023;
        int cp = e & 31;
        int j  = e >> 5;
        if (which < 3) {
            const float* w = (which == 0) ? wq : ((which == 1) ? wk : wv);
            const float* Wrow = in_w + (which * 32 + cp) * 32;
            float acc = 0.f;
            #pragma unroll
            for (int t = 0; t < 32; ++t) acc += Wrow[t] * w[t * 32 + j];
            M[which * 1024 + j * 32 + cp] = acc;
        } else {
            M[3 * 1024 + j * 32 + cp] = out_w[cp * 32 + j];
        }
    } else if (blk == 16) {
        int tid = threadIdx.x;
        if (tid < 32) {
            float a = 0.f, b = 0.f, c = 0.f;
            #pragma unroll
            for (int t = 0; t < 32; ++t) {
                a += in_w[tid * 32 + t] * bq[t];
                b += in_w[(32 + tid) * 32 + t] * bk[t];
                c += in_w[(64 + tid) * 32 + t] * bv[t];
            }
            V[tid]      = a + in_b[tid];
            V[32 + tid] = b;
            V[64 + tid] = c;
        } else if (tid < 128) {
            int grp = (tid - 32) >> 5;   // 0=PWy 1=PWx 2=pb3
            int cp  = tid & 31;
            float acc = 0.f;
            #pragma unroll
            for (int t = 0; t < 32; ++t) {
                float src = (grp == 0) ? pos_w[t * 2 + 0] : ((grp == 1) ? pos_w[t * 2 + 1] : pos_b[t]);
                acc += in_w[(64 + cp) * 32 + t] * src;
            }
            V[96 + grp * 32 + cp] = acc;
        }
    } else {
        // blocks 17..80: zero the 512 KB flag map (131072 ints; 64 blocks x 256 thr x 8 ints)
        int base = (blk - 17) * 2048 + threadIdx.x * 8;
        int4 z = {0, 0, 0, 0};
        *(int4*)(fmap_i + base)     = z;
        *(int4*)(fmap_i + base + 4) = z;
    }
}

// ---------------- stage1: point-parallel LN + fused q/k/v linears (pixel-dense out) ----------------
// CHANGE vs r0: weight matrices read as float4 (256 VMEM issues per matrix instead of
// 1024) — the 3x1024 scalar dword loads were the dominant issue-rate cost of this
// kernel. float4 accumulators also invite v_pk_fma_f32 packing.
__global__ __launch_bounds__(256) void stage1(const float* __restrict__ feats,
                                              const int* __restrict__ coors,
                                              const float* __restrict__ ln_w,
                                              const float* __restrict__ ln_b,
                                              const float* __restrict__ M,
                                              const float* __restrict__ V,
                                              __half* __restrict__ qh,
                                              __half* __restrict__ kvh,
                                              unsigned char* __restrict__ fmap) {
    int gp = blockIdx.x * 256 + threadIdx.x;
    if (gp >= NPTS) return;
    int b = (gp >= NN) ? 1 : 0;
    int2 yx = ((const int2*)coors)[gp];
    int pix = (b << 18) + (yx.x << 9) + yx.y;

    const float* fr = feats + ((size_t)gp << 5);
    float x[32];
    #pragma unroll
    for (int k = 0; k < 8; ++k) ((float4*)x)[k] = ((const float4*)fr)[k];

    float s1 = 0.f, s2 = 0.f;
    #pragma unroll
    for (int j = 0; j < 32; ++j) { s1 += x[j]; s2 += x[j] * x[j]; }
    float mu   = s1 * (1.f / 32.f);
    float var  = s2 * (1.f / 32.f) - mu * mu;
    float rstd = rsqrtf(var + 1e-5f);
    #pragma unroll
    for (int j = 0; j < 32; ++j) x[j] = (x[j] - mu) * rstd * ln_w[j] + ln_b[j];

    const float4* M4 = (const float4*)M;   // M[j*32+c] == M4[j*8 + c/4]
    const float4* V4 = (const float4*)V;

    float4 a4[8];
    __half2 hbuf[16];

    // q' = x @ Mq + bq'  -> fp16 at pixel slot
    #pragma unroll
    for (int c = 0; c < 8; ++c) a4[c] = V4[c];
    #pragma unroll
    for (int j = 0; j < 32; ++j) {
        float xv = x[j];
        #pragma unroll
        for (int c = 0; c < 8; ++c) {
            float4 m = M4[j * 8 + c];
            a4[c].x += xv * m.x; a4[c].y += xv * m.y;
            a4[c].z += xv * m.z; a4[c].w += xv * m.w;
        }
    }
    #pragma unroll
    for (int c = 0; c < 8; ++c) {
        hbuf[2 * c]     = __floats2half2_rn(a4[c].x, a4[c].y);
        hbuf[2 * c + 1] = __floats2half2_rn(a4[c].z, a4[c].w);
    }
    {
        float4* qd = (float4*)(qh + ((size_t)pix << 5));
        #pragma unroll
        for (int k = 0; k < 4; ++k) qd[k] = ((float4*)hbuf)[k];
    }

    __half2 kvbuf[32];   // 128 B: k halves [0:16), v halves [16:32)

    // k' = x @ Mk + bk'  -> fp16
    #pragma unroll
    for (int c = 0; c < 8; ++c) a4[c] = V4[8 + c];
    #pragma unroll
    for (int j = 0; j < 32; ++j) {
        float xv = x[j];
        #pragma unroll
        for (int c = 0; c < 8; ++c) {
            float4 m = M4[256 + j * 8 + c];
            a4[c].x += xv * m.x; a4[c].y += xv * m.y;
            a4[c].z += xv * m.z; a4[c].w += xv * m.w;
        }
    }
    #pragma unroll
    for (int c = 0; c < 8; ++c) {
        kvbuf[2 * c]     = __floats2half2_rn(a4[c].x, a4[c].y);
        kvbuf[2 * c + 1] = __floats2half2_rn(a4[c].z, a4[c].w);
    }

    // v' = x @ Mv + bv'  -> fp16
    #pragma unroll
    for (int c = 0; c < 8; ++c) a4[c] = V4[16 + c];
    #pragma unroll
    for (int j = 0; j < 32; ++j) {
        float xv = x[j];
        #pragma unroll
        for (int c = 0; c < 8; ++c) {
            float4 m = M4[512 + j * 8 + c];
            a4[c].x += xv * m.x; a4[c].y += xv * m.y;
            a4[c].z += xv * m.z; a4[c].w += xv * m.w;
        }
    }
    #pragma unroll
    for (int c = 0; c < 8; ++c) {
        kvbuf[16 + 2 * c] = __floats2half2_rn(a4[c].x, a4[c].y);
        kvbuf[17 + 2 * c] = __floats2half2_rn(a4[c].z, a4[c].w);
    }

    float4* kd = (float4*)(kvh + ((size_t)pix << 6));
    #pragma unroll
    for (int k = 0; k < 8; ++k) kd[k] = ((float4*)kvbuf)[k];

    fmap[pix] = 1;
}

// ---------------- stage23: fused attention + out-proj + canvas write (r0-exact) ----------------
// Block = one 256-pixel window. kv/q addresses are pure pixel arithmetic (no rank
// indirection); flag map (512 KB, L2-resident) gates validity + pos term.
__global__ __launch_bounds__(256) void stage23(const unsigned char* __restrict__ fmap,
                                               const __half* __restrict__ qh,
                                               const __half* __restrict__ kvh,
                                               const float* __restrict__ M,
                                               const float* __restrict__ V,
                                               const float* __restrict__ in_b,
                                               const float* __restrict__ out_b,
                                               float* __restrict__ out) {
    __shared__ __half2 lso[256 * 17];   // 17 half2 (68 B) stride per point
    __shared__ int lsp[256];
    __shared__ int woff[4];

    int w = (blockIdx.x & 7) * 256 + (blockIdx.x >> 3);   // XCD-swizzled window index
    int tid = threadIdx.x;
    int pix = w * 256 + tid;

    bool occ = fmap[pix] != 0;
    unsigned long long mask = __ballot(occ);
    int lane = tid & 63, wvi = tid >> 6;
    if (lane == 0) woff[wvi] = __popcll(mask);
    __syncthreads();
    int pre = 0;
    for (int ww = 0; ww < wvi; ++ww) pre += woff[ww];
    int cnt = woff[0] + woff[1] + woff[2] + woff[3];
    int slot = -1;
    if (occ) {
        slot = pre + __popcll(mask & ((1ull << lane) - 1ull));
        lsp[slot] = tid;
    }
    __syncthreads();

    const int DYC[9] = {0,-1,1,0,-1,1,0,-1,1};
    const int DXC[9] = {0,0,0,1,1,1,-1,-1,-1};

    // ---- phase A: attention, one thread per occupied pixel ----
    if (tid < cnt) {
        int pixl = w * 256 + lsp[tid];
        int b = pixl >> 18;
        int p = pixl & (HWPIX - 1);
        int y = p >> 9, x = p & 511;

        float qf[32];
        {
            const float4* q4 = (const float4*)(qh + ((size_t)pixl << 5));
            float4 r0 = q4[0], r1 = q4[1], r2 = q4[2], r3 = q4[3];
            h8_to_f8(r0, qf); h8_to_f8(r1, qf + 8); h8_to_f8(r2, qf + 16); h8_to_f8(r3, qf + 24);
        }

        // 9 taps: validity is arithmetic + one independent flag byte each (no load chain)
        int np[9];
        bool nv[9];
        #pragma unroll
        for (int s = 0; s < 9; ++s) {
            int sy = y + DYC[s], sx = x + DXC[s];
            bool inb = (sy >= 0) & (sy < HH) & (sx >= 0) & (sx < WW);
            int npx = (b << 18) + (sy << 9) + sx;
            np[s] = npx;
            nv[s] = inb ? (fmap[npx] != 0) : false;
        }

        float eb0 = 0.f, eb1 = 0.f;
        #pragma unroll
        for (int c = 0; c < 16; ++c) {
            eb0 += qf[c]      * in_b[32 + c];
            eb1 += qf[16 + c] * in_b[48 + c];
        }

        float lg0[9], lg1[9];
        #pragma unroll
        for (int s = 0; s < 9; ++s) {
            float d0 = eb0, d1 = eb1;
            if (nv[s]) {
                const float4* kp = (const float4*)(kvh + ((size_t)np[s] << 6));
                float kf[32];
                h8_to_f8(kp[0], kf);      h8_to_f8(kp[1], kf + 8);
                h8_to_f8(kp[2], kf + 16); h8_to_f8(kp[3], kf + 24);
                #pragma unroll
                for (int c = 0; c < 16; ++c) {
                    d0 += qf[c]      * kf[c];
                    d1 += qf[16 + c] * kf[16 + c];
                }
            }
            lg0[s] = d0 * 0.25f;   // 1/sqrt(HD=16)
            lg1[s] = d1 * 0.25f;
        }
        float m0 = lg0[0], m1 = lg1[0];
        #pragma unroll
        for (int s = 1; s < 9; ++s) { m0 = fmaxf(m0, lg0[s]); m1 = fmaxf(m1, lg1[s]); }
        float l0 = 0.f, l1 = 0.f;
        #pragma unroll
        for (int s = 0; s < 9; ++s) {
            lg0[s] = __expf(lg0[s] - m0); l0 += lg0[s];
            lg1[s] = __expf(lg1[s] - m1); l1 += lg1[s];
        }

        float o[32];
        #pragma unroll
        for (int c = 0; c < 32; ++c) o[c] = 0.f;
        float wdy0 = 0.f, wdx0 = 0.f, woc0 = 0.f;
        float wdy1 = 0.f, wdx1 = 0.f, woc1 = 0.f;
        #pragma unroll
        for (int s = 0; s < 9; ++s) {
            if (nv[s]) {
                float w0 = lg0[s], w1 = lg1[s];
                const float4* vp = (const float4*)(kvh + ((size_t)np[s] << 6)) + 4;
                float vf[32];
                h8_to_f8(vp[0], vf);      h8_to_f8(vp[1], vf + 8);
                h8_to_f8(vp[2], vf + 16); h8_to_f8(vp[3], vf + 24);
                #pragma unroll
                for (int c = 0; c < 16; ++c) {
                    o[c]      += w0 * vf[c];
                    o[16 + c] += w1 * vf[16 + c];
                }
                wdy0 += w0 * (float)DYC[s]; wdx0 += w0 * (float)DXC[s]; woc0 += w0;
                wdy1 += w1 * (float)DYC[s]; wdx1 += w1 * (float)DXC[s]; woc1 += w1;
            }
        }
        float rl0 = 1.f / l0, rl1 = 1.f / l1;
        #pragma unroll
        for (int c = 0; c < 16; ++c) {
            o[c]      = (o[c]      + wdy0 * V[96 + c]      + wdx0 * V[128 + c]      + woc0 * V[160 + c])      * rl0 + in_b[64 + c];
            o[16 + c] = (o[16 + c] + wdy1 * V[96 + 16 + c] + wdx1 * V[128 + 16 + c] + woc1 * V[160 + 16 + c]) * rl1 + in_b[80 + c];
        }

        // out projection: all 32 channels, wave-uniform (scalarized) weights
        float acc[32];
        #pragma unroll
        for (int c = 0; c < 32; ++c) acc[c] = out_b[c];
        #pragma unroll
        for (int j = 0; j < 32; ++j) {
            float vj = o[j];
            #pragma unroll
            for (int c = 0; c < 32; ++c) acc[c] += vj * M[3072 + j * 32 + c];
        }

        // pack fp16 into LDS row (stride 17 half2)
        __half2* lrow = lso + tid * 17;
        #pragma unroll
        for (int c = 0; c < 16; ++c) lrow[c] = __floats2half2_rn(acc[2 * c], acc[2 * c + 1]);
    }
    __syncthreads();

    // ---- phase B: canvas write (all 256 threads; 256 B contiguous per wave-instr) ----
    int b = pix >> 18;
    int p = pix & (HWPIX - 1);
    float* outb = out + (size_t)b * CC * HWPIX + p;
    if (occ) {
        const __half2* lrow = lso + slot * 17;
        #pragma unroll
        for (int c2 = 0; c2 < 16; ++c2) {
            float2 f = __half22float2(lrow[c2]);
            outb[(2 * c2) * HWPIX]     = f.x;
            outb[(2 * c2 + 1) * HWPIX] = f.y;
        }
    } else {
        #pragma unroll
        for (int cc = 0; cc < 32; ++cc) outb[cc * HWPIX] = 0.f;
    }
}

extern "C" void kernel_launch(void* const* d_in, const int* in_sizes, int n_in,
                              void* d_out, int out_size, void* d_ws, size_t ws_size,
                              hipStream_t stream) {
    const float* feats = (const float*)d_in[0];
    const int*   coors = (const int*)d_in[1];
    const float* ln_w  = (const float*)d_in[2];
    const float* ln_b  = (const float*)d_in[3];
    const float* wq    = (const float*)d_in[4];
    const float* bq    = (const float*)d_in[5];
    const float* wk    = (const float*)d_in[6];
    const float* bk    = (const float*)d_in[7];
    const float* wv    = (const float*)d_in[8];
    const float* bv    = (const float*)d_in[9];
    const float* pos_w = (const float*)d_in[10];
    const float* pos_b = (const float*)d_in[11];
    const float* in_w  = (const float*)d_in[12];
    const float* in_b  = (const float*)d_in[13];
    const float* out_w = (const float*)d_in[14];
    const float* out_b = (const float*)d_in[15];

    // workspace layout (pixel-dense)
    float*  M    = (float*)d_ws;                                        // 4096
    float*  V    = M + 4096;                                            // 192
    __half* qh   = (__half*)(V + 192);                                  // NPIX*32 halves (33.5 MB)
    __half* kvh  = qh + (size_t)NPIX * 32;                              // NPIX*64 halves (67.1 MB)
    unsigned char* fmap = (unsigned char*)(kvh + (size_t)NPIX * 64);    // NPIX bytes (0.5 MB)
    size_t need = (4096 + 192) * 4 + (size_t)NPIX * 96 * 2 + (size_t)NPIX;
    if (ws_size < need) {
        fprintf(stderr, "kernel_launch: ws too small: %zu < %zu\n", ws_size, need);
        return;
    }

    prep<<<81, 256, 0, stream>>>(wq, wk, wv, in_w, out_w, bq, bk, bv, in_b, pos_w, pos_b,
                                 M, V, (int*)fmap);
    stage1<<<(NPTS + 255) / 256, 256, 0, stream>>>(feats, coors, ln_w, ln_b, M, V, qh, kvh, fmap);
    stage23<<<NBLK, 256, 0, stream>>>(fmap, qh, kvh, M, V, in_b, out_b, (float*)d_out);
}